// Round 5
// baseline (761.921 us; speedup 1.0000x reference)
//
#include <hip/hip_runtime.h>
#include <hip/hip_bf16.h>
#include <cstdint>

// MCRNNVAE eval forward, algebraically collapsed:
//   h_{t+1} = tanh(x_t@R_c + r0_c + h_t@Q_c)
//   mu_t    = x_t@N_c + h_t@M2_c + n0_c
// R,Q,N,M2,r0,n0 precomputed from the raw weights (exact linear algebra).
// Round 9: round-8 structure with the correctness bug fixed: hI inner dim was
// 129 but col indexes 0..255 (one u32 = hi|lo PER COLUMN) -> out-of-bounds LDS
// writes corrupted h. Now hI[2][16][257]; stride 257 dw == 1 (mod 32) gives
// read banks (m+8q)%32 = max 2-way aliasing (free). Everything else unchanged:
// interleaved hi/lo plane (8 ds_write_b32/thread), v_perm repack on read,
// transposed U [ct][col][512] (b64 loads/stores), single barrier, 4 acc chains.

typedef __attribute__((ext_vector_type(8))) short short8;
typedef __attribute__((ext_vector_type(4))) short short4v;
typedef __attribute__((ext_vector_type(4))) float float4v;

__device__ __forceinline__ float bf2f(unsigned short u){
  union { unsigned int i; float f; } v; v.i = ((unsigned int)u) << 16; return v.f;
}
__device__ __forceinline__ unsigned short f2bf(float f){
  union { float f; unsigned int i; } v; v.f = f;
  unsigned int r = v.i + 0x7fffu + ((v.i >> 16) & 1u);
  return (unsigned short)(r >> 16);
}
__device__ __forceinline__ void st_bf2(unsigned short* p, float a, float b){
  unsigned int pa = f2bf(a), pb = f2bf(b);
  *(unsigned int*)p = pa | (pb << 16);
}
__device__ __forceinline__ float ftanh(float x){
  x = fminf(15.f, fmaxf(-15.f, x));
  float e = __expf(2.f * x);
  return (e - 1.f) * __builtin_amdgcn_rcpf(e + 1.f);
}

__device__ __forceinline__ float dotSB(const float* __restrict__ a,
                                       const float* __restrict__ b, int K, int ldb){
  float s = 0.f;
  #pragma unroll 4
  for (int k = 0; k < K; ++k) s = fmaf(a[k], b[(size_t)k * ldb], s);
  return s;
}

// ---- precompute stage 1: T1 = We1@Wqm, T2 = We2@Wqm, c0a = be@Wqm + bqm
__global__ void pre1(const float* __restrict__ encW, const float* __restrict__ encb,
                     const float* __restrict__ Wqm, const float* __restrict__ bqm,
                     float* __restrict__ T1, float* __restrict__ T2, float* __restrict__ c0a){
  int i = blockIdx.x * 256 + threadIdx.x;
  if (i < 24576){
    int c = i >> 13, rr = (i >> 6) & 127, l = i & 63;
    T1[i] = dotSB(encW + ((size_t)c*384 + rr)*128, Wqm + (size_t)c*8192 + l, 128, 64);
  } else if (i < 73728){
    int j = i - 24576; int c = j >> 14, rr = (j >> 6) & 255, l = j & 63;
    T2[j] = dotSB(encW + ((size_t)c*384 + 128 + rr)*128, Wqm + (size_t)c*8192 + l, 128, 64);
  } else if (i < 73920){
    int j = i - 73728; int c = j >> 6, l = j & 63;
    c0a[j] = dotSB(encb + c*128, Wqm + (size_t)c*8192 + l, 128, 64) + bqm[j];
  }
}

// ---- stage 2: A = T1@Wz, Bm = T2@Wz, c0 = c0a@Wz + bz
__global__ void pre2(const float* __restrict__ T1, const float* __restrict__ T2,
                     const float* __restrict__ c0a, const float* __restrict__ Wz,
                     const float* __restrict__ bz,
                     float* __restrict__ A, float* __restrict__ Bm, float* __restrict__ c0){
  int i = blockIdx.x * 256 + threadIdx.x;
  if (i < 49152){
    int c = i >> 14, rr = (i >> 7) & 127, n = i & 127;
    A[i] = dotSB(T1 + ((size_t)c*128 + rr)*64, Wz + n, 64, 128);
  } else if (i < 147456){
    int j = i - 49152; int c = j >> 15, rr = (j >> 7) & 255, n = j & 127;
    Bm[j] = dotSB(T2 + ((size_t)c*256 + rr)*64, Wz + n, 64, 128);
  } else if (i < 147840){
    int j = i - 147456; int c = j >> 7, n = j & 127;
    c0[j] = dotSB(c0a + c*64, Wz + n, 64, 128) + bz[n];
  }
}

// ---- stage 3: P = Wi1 + A@Wi2; Q = Whh + Bm@Wi2; r = c0@Wi2 + bih + bhh;
//               D1 = A@Wd1; E1 = Wd2 + Bm@Wd1; m0a = c0@Wd1 + bd
__global__ void pre3(const float* __restrict__ A, const float* __restrict__ Bm,
                     const float* __restrict__ c0, const float* __restrict__ Wih,
                     const float* __restrict__ Whh, const float* __restrict__ bih,
                     const float* __restrict__ bhh, const float* __restrict__ decW,
                     const float* __restrict__ decb,
                     float* __restrict__ P, float* __restrict__ Q, float* __restrict__ r,
                     float* __restrict__ D1, float* __restrict__ E1, float* __restrict__ m0a){
  int i = blockIdx.x * 256 + threadIdx.x;
  const float* Wi2 = Wih + 128*256;
  if (i < 98304){
    int c = i >> 15, rr = (i >> 8) & 127, n = i & 255;
    P[i] = Wih[rr*256 + n] + dotSB(A + ((size_t)c*128 + rr)*128, Wi2 + n, 128, 256);
  } else if (i < 294912){
    int j = i - 98304; int c = j >> 16, rr = (j >> 8) & 255, n = j & 255;
    Q[j] = Whh[rr*256 + n] + dotSB(Bm + ((size_t)c*256 + rr)*128, Wi2 + n, 128, 256);
  } else if (i < 295680){
    int j = i - 294912; int c = j >> 8, n = j & 255;
    r[j] = dotSB(c0 + c*128, Wi2 + n, 128, 256) + bih[n] + bhh[n];
  } else if (i < 344832){
    int j = i - 295680; int c = j >> 14, rr = (j >> 7) & 127, n = j & 127;
    D1[j] = dotSB(A + ((size_t)c*128 + rr)*128, decW + (size_t)c*49152 + n, 128, 128);
  } else if (i < 443136){
    int j = i - 344832; int c = j >> 15, rr = (j >> 7) & 255, n = j & 127;
    E1[j] = decW[(size_t)c*49152 + (size_t)(128 + rr)*128 + n]
          + dotSB(Bm + ((size_t)c*256 + rr)*128, decW + (size_t)c*49152 + n, 128, 128);
  } else if (i < 443520){
    int j = i - 443136; int c = j >> 7, n = j & 127;
    m0a[j] = dotSB(c0 + c*128, decW + (size_t)c*49152 + n, 128, 128) + decb[j];
  }
}

// ---- stage 4: R = Wx@P; r0 = bx@P + r; M1 = D1@Wpm; M2 = E1@Wpm; m0 = m0a@Wpm + bpm
__global__ void pre4(const float* __restrict__ Wx, const float* __restrict__ bx,
                     const float* __restrict__ P, const float* __restrict__ r,
                     const float* __restrict__ D1, const float* __restrict__ E1,
                     const float* __restrict__ m0a, const float* __restrict__ Wpm,
                     const float* __restrict__ bpm,
                     float* __restrict__ R, float* __restrict__ r0,
                     float* __restrict__ M1, float* __restrict__ M2, float* __restrict__ m0){
  int i = blockIdx.x * 256 + threadIdx.x;
  if (i < 98304){
    int c = i >> 15, rr = (i >> 8) & 127, n = i & 255;
    R[i] = dotSB(Wx + ((size_t)c*128 + rr)*128, P + (size_t)c*32768 + n, 128, 256);
  } else if (i < 99072){
    int j = i - 98304; int c = j >> 8, n = j & 255;
    r0[j] = dotSB(bx + c*128, P + (size_t)c*32768 + n, 128, 256) + r[j];
  } else if (i < 148224){
    int j = i - 99072; int c = j >> 14, rr = (j >> 7) & 127, n = j & 127;
    M1[j] = dotSB(D1 + ((size_t)c*128 + rr)*128, Wpm + (size_t)c*16384 + n, 128, 128);
  } else if (i < 246528){
    int j = i - 148224; int c = j >> 15, rr = (j >> 7) & 255, n = j & 127;
    M2[j] = dotSB(E1 + ((size_t)c*256 + rr)*128, Wpm + (size_t)c*16384 + n, 128, 128);
  } else if (i < 246912){
    int j = i - 246528; int c = j >> 7, n = j & 127;
    m0[j] = dotSB(m0a + c*128, Wpm + (size_t)c*16384 + n, 128, 128) + bpm[j];
  }
}

// ---- stage 5: Nn = Wx@M1; n0 = bx@M1 + m0
__global__ void pre5(const float* __restrict__ Wx, const float* __restrict__ bx,
                     const float* __restrict__ M1, const float* __restrict__ m0,
                     float* __restrict__ Nn, float* __restrict__ n0){
  int i = blockIdx.x * 256 + threadIdx.x;
  if (i < 49152){
    int c = i >> 14, rr = (i >> 7) & 127, n = i & 127;
    Nn[i] = dotSB(Wx + ((size_t)c*128 + rr)*128, M1 + (size_t)c*16384 + n, 128, 128);
  } else if (i < 49536){
    int j = i - 49152; int c = j >> 7, n = j & 127;
    n0[j] = dotSB(bx + c*128, M1 + (size_t)c*16384 + n, 128, 128) + m0[j];
  }
}

#define MFMA_BF16 __builtin_amdgcn_mfma_f32_16x16x32_bf16

// ---- kernU2: U^T = (x@R + r0)^T (bf16) via MFMA. 1200 blocks x 512 thr.
// U layout TRANSPOSED: U[(c*100+t)*256 + col][512 batch rows] -> each thread
// stores its 4 consecutive C-rows per column as one b64 (16 stores, was 64).
__global__ __launch_bounds__(512, 2)
void kernU2(const float* __restrict__ x, const float* __restrict__ Rg,
            const float* __restrict__ r0g, unsigned short* __restrict__ U){
  __shared__ unsigned short xs[128][136];
  const int m0 = blockIdx.x * 128;
  const int c  = m0 / 51200;                   // 400 blocks/channel, no straddle
  const int w  = threadIdx.x >> 6;
  const int l  = threadIdx.x & 63;
  const int q  = l >> 4, m = l & 15;
  const float* __restrict__ Rc = Rg + (size_t)c * 32768;   // [128][256]

  short8 rf[4][2];
  #pragma unroll
  for (int kt = 0; kt < 4; ++kt)
    #pragma unroll
    for (int nt = 0; nt < 2; ++nt){
      union { short8 v; unsigned short u[8]; } tmp;
      const int col = 32*w + 16*nt + m;
      #pragma unroll
      for (int j = 0; j < 8; ++j)
        tmp.u[j] = f2bf(Rc[(size_t)(32*kt + 8*q + j)*256 + col]);
      rf[kt][nt] = tmp.v;
    }
  const float r0v0 = r0g[c*256 + 32*w + m];
  const float r0v1 = r0g[c*256 + 32*w + 16 + m];

  {
    const int r  = threadIdx.x >> 2;
    const int c0 = (threadIdx.x & 3) * 32;
    const float* xr = x + (size_t)(m0 + r)*128 + c0;
    #pragma unroll
    for (int i = 0; i < 8; ++i){
      float4 v = *(const float4*)(xr + 4*i);
      st_bf2(&xs[r][c0 + 4*i],     v.x, v.y);
      st_bf2(&xs[r][c0 + 4*i + 2], v.z, v.w);
    }
  }
  __syncthreads();

  const size_t ct = (size_t)(m0 >> 9);         // c*100 + t (block within one t)
  const int bbase = (m0 & 511);

  #pragma unroll 1
  for (int mt = 0; mt < 8; ++mt){
    float4v a0 = { r0v0, r0v0, r0v0, r0v0 };
    float4v a1 = { r0v1, r0v1, r0v1, r0v1 };
    #pragma unroll
    for (int kt = 0; kt < 4; ++kt){
      short8 af = *(const short8*)&xs[16*mt + m][32*kt + 8*q];
      a0 = MFMA_BF16(af, rf[kt][0], a0, 0,0,0);
      a1 = MFMA_BF16(af, rf[kt][1], a1, 0,0,0);
    }
    const int b = bbase + 16*mt + 4*q;         // 4 consecutive C-rows
    short4v s0, s1;
    s0[0] = (short)f2bf(a0.x); s0[1] = (short)f2bf(a0.y);
    s0[2] = (short)f2bf(a0.z); s0[3] = (short)f2bf(a0.w);
    s1[0] = (short)f2bf(a1.x); s1[1] = (short)f2bf(a1.y);
    s1[2] = (short)f2bf(a1.z); s1[3] = (short)f2bf(a1.w);
    *(short4v*)(U + (ct*256 + 32*w + m)*512 + b)      = s0;
    *(short4v*)(U + (ct*256 + 32*w + 16 + m)*512 + b) = s1;
  }
}

// ---- kernB5: recurrence h_{t+1} = tanh(U_t + h_t@Q_c) via MFMA.
// 96 blocks x 512 thr (8 waves). Interleaved hi/lo LDS plane hI[2][16][257]
// (u32 = hi | lo<<16 per column; stride 257 dw == 1 mod 32 -> banks (m+8q)%32,
// max 2-way = free). 8 ds_write_b32 writeback, v_perm repack on b128 reads,
// transposed-U b64 loads, single barrier/step, 4 independent acc chains.
__global__ __launch_bounds__(512, 2)
void kernB5(const unsigned short* __restrict__ U, const float* __restrict__ Qg,
            const float* __restrict__ h0, unsigned short* __restrict__ Hs){
  __shared__ unsigned int hI[2][16][257];      // 257: col 0..255 + bank-spread
  const int c  = blockIdx.x >> 5;
  const int b0 = (blockIdx.x & 31) << 4;
  const int w  = threadIdx.x >> 6;
  const int l  = threadIdx.x & 63;
  const int q  = l >> 4, m = l & 15;
  const float* __restrict__ Qc = Qg + (size_t)c * 65536;

  short8 qf[8][2];
  #pragma unroll
  for (int kt = 0; kt < 8; ++kt)
    #pragma unroll
    for (int nt = 0; nt < 2; ++nt){
      union { short8 v; unsigned short u[8]; } tmp;
      const int col = 32*w + 16*nt + m;
      #pragma unroll
      for (int j = 0; j < 8; ++j)
        tmp.u[j] = f2bf(Qc[(size_t)(32*kt + 8*q + j)*256 + col]);
      qf[kt][nt] = tmp.v;
    }

  unsigned short hiR[8];
  #pragma unroll
  for (int nt = 0; nt < 2; ++nt){
    const int col = 32*w + 16*nt + m;
    #pragma unroll
    for (int r = 0; r < 4; ++r){
      const int row = 4*q + r;
      float v = h0[((size_t)c*512 + b0 + row)*256 + col];
      unsigned short hi = f2bf(v);
      hiR[nt*4 + r] = hi;
      hI[0][row][col] = (unsigned int)hi | ((unsigned int)f2bf(v - bf2f(hi)) << 16);
    }
  }
  __syncthreads();

  // U (transposed): thread needs rows b0+4q..+3 at cols 32w+m, 32w+16+m
  const unsigned short* Ub0 = U + ((size_t)(c*100)*256 + 32*w + m)*512 + b0 + 4*q;
  const unsigned short* Ub1 = U + ((size_t)(c*100)*256 + 32*w + 16 + m)*512 + b0 + 4*q;
  short4v un0 = *(const short4v*)Ub0;
  short4v un1 = *(const short4v*)Ub1;

  #pragma unroll 1
  for (int t = 0; t < 100; ++t){
    const int cur = t & 1, nxt = cur ^ 1;

    // store h_t (bf16) to Hs — fire-and-forget
    const size_t rowbase = (size_t)(c*100 + t)*512 + b0;
    #pragma unroll
    for (int nt = 0; nt < 2; ++nt)
      #pragma unroll
      for (int r = 0; r < 4; ++r)
        Hs[(rowbase + 4*q + r)*256 + 32*w + 16*nt + m] = hiR[nt*4 + r];

    // acc chains: hi seeded with U_t, lo zero (summed before tanh)
    float4v a0h = { bf2f((unsigned short)un0[0]), bf2f((unsigned short)un0[1]),
                    bf2f((unsigned short)un0[2]), bf2f((unsigned short)un0[3]) };
    float4v a1h = { bf2f((unsigned short)un1[0]), bf2f((unsigned short)un1[1]),
                    bf2f((unsigned short)un1[2]), bf2f((unsigned short)un1[3]) };
    float4v a0l = { 0.f, 0.f, 0.f, 0.f };
    float4v a1l = { 0.f, 0.f, 0.f, 0.f };

    // prefetch U_{t+1} (2 x b64; waited on at copy point after MFMAs)
    const int tn = (t < 99) ? t + 1 : 99;
    short4v unN0 = *(const short4v*)(Ub0 + (size_t)tn*131072);
    short4v unN1 = *(const short4v*)(Ub1 + (size_t)tn*131072);

    const unsigned int* hrow = &hI[cur][m][0];
    #pragma unroll
    for (int kt = 0; kt < 8; ++kt){
      uint4 u0 = *(const uint4*)(hrow + 32*kt + 8*q);
      uint4 u1 = *(const uint4*)(hrow + 32*kt + 8*q + 4);
      union { short8 v; unsigned int d[4]; } ahi, alo;
      ahi.d[0] = __builtin_amdgcn_perm(u0.y, u0.x, 0x05040100u);
      ahi.d[1] = __builtin_amdgcn_perm(u0.w, u0.z, 0x05040100u);
      ahi.d[2] = __builtin_amdgcn_perm(u1.y, u1.x, 0x05040100u);
      ahi.d[3] = __builtin_amdgcn_perm(u1.w, u1.z, 0x05040100u);
      alo.d[0] = __builtin_amdgcn_perm(u0.y, u0.x, 0x07060302u);
      alo.d[1] = __builtin_amdgcn_perm(u0.w, u0.z, 0x07060302u);
      alo.d[2] = __builtin_amdgcn_perm(u1.y, u1.x, 0x07060302u);
      alo.d[3] = __builtin_amdgcn_perm(u1.w, u1.z, 0x07060302u);
      a0h = MFMA_BF16(ahi.v, qf[kt][0], a0h, 0,0,0);
      a1h = MFMA_BF16(ahi.v, qf[kt][1], a1h, 0,0,0);
      a0l = MFMA_BF16(alo.v, qf[kt][0], a0l, 0,0,0);
      a1l = MFMA_BF16(alo.v, qf[kt][1], a1l, 0,0,0);
    }

    float hn[8];
    hn[0] = ftanh(a0h.x + a0l.x); hn[1] = ftanh(a0h.y + a0l.y);
    hn[2] = ftanh(a0h.z + a0l.z); hn[3] = ftanh(a0h.w + a0l.w);
    hn[4] = ftanh(a1h.x + a1l.x); hn[5] = ftanh(a1h.y + a1l.y);
    hn[6] = ftanh(a1h.z + a1l.z); hn[7] = ftanh(a1h.w + a1l.w);

    // write h_{t+1} into NEXT buffer as packed hi|lo (8 x ds_write_b32)
    #pragma unroll
    for (int nt = 0; nt < 2; ++nt){
      const int col = 32*w + 16*nt + m;
      #pragma unroll
      for (int r = 0; r < 4; ++r){
        const int row = 4*q + r;
        float v = hn[nt*4 + r];
        unsigned short hi = f2bf(v);
        hiR[nt*4 + r] = hi;
        hI[nxt][row][col] = (unsigned int)hi | ((unsigned int)f2bf(v - bf2f(hi)) << 16);
      }
    }
    un0 = unN0; un1 = unN1;

    __syncthreads();   // single barrier per step
  }
}

// ---- kernC3: out = x@Nn + Hs@M2 + n0 via MFMA. 1200 blocks x 512 thr. (proven)
__global__ __launch_bounds__(512, 2)
void kernC3(const float* __restrict__ x, const unsigned short* __restrict__ Hs,
            const float* __restrict__ Nn, const float* __restrict__ M2,
            const float* __restrict__ n0, float* __restrict__ out){
  __shared__ unsigned short xs[128][136];
  const int m0 = blockIdx.x * 128;
  const int c  = m0 / 51200;
  const int w  = threadIdx.x >> 6;
  const int l  = threadIdx.x & 63;
  const int q  = l >> 4, m = l & 15;
  const int col = 16*w + m;
  const float* __restrict__ Nc  = Nn + (size_t)c * 16384;   // [128][128]
  const float* __restrict__ M2c = M2 + (size_t)c * 32768;   // [256][128]

  short8 bw[12];
  #pragma unroll
  for (int kt = 0; kt < 4; ++kt){
    union { short8 v; unsigned short u[8]; } tmp;
    #pragma unroll
    for (int j = 0; j < 8; ++j)
      tmp.u[j] = f2bf(Nc[(size_t)(32*kt + 8*q + j)*128 + col]);
    bw[kt] = tmp.v;
  }
  #pragma unroll
  for (int kt = 0; kt < 8; ++kt){
    union { short8 v; unsigned short u[8]; } tmp;
    #pragma unroll
    for (int j = 0; j < 8; ++j)
      tmp.u[j] = f2bf(M2c[(size_t)(32*kt + 8*q + j)*128 + col]);
    bw[4 + kt] = tmp.v;
  }
  const float nz = n0[c*128 + col];

  {
    const int r  = threadIdx.x >> 2;
    const int c0 = (threadIdx.x & 3) * 32;
    const float* xr = x + (size_t)(m0 + r)*128 + c0;
    #pragma unroll
    for (int i = 0; i < 8; ++i){
      float4 v = *(const float4*)(xr + 4*i);
      st_bf2(&xs[r][c0 + 4*i],     v.x, v.y);
      st_bf2(&xs[r][c0 + 4*i + 2], v.z, v.w);
    }
  }
  __syncthreads();

  #pragma unroll 1
  for (int mt = 0; mt < 8; ++mt){
    float4v aa = { nz, nz, nz, nz }, ab = { 0.f, 0.f, 0.f, 0.f };
    #pragma unroll
    for (int kt = 0; kt < 4; ++kt){
      short8 af = *(const short8*)&xs[16*mt + m][32*kt + 8*q];
      if (kt & 1) ab = MFMA_BF16(af, bw[kt], ab, 0,0,0);
      else        aa = MFMA_BF16(af, bw[kt], aa, 0,0,0);
    }
    const size_t mrow = (size_t)(m0 + 16*mt) + m;
    #pragma unroll
    for (int kt = 0; kt < 8; ++kt){
      short8 af = *(const short8*)&Hs[mrow*256 + 32*kt + 8*q];
      if (kt & 1) ab = MFMA_BF16(af, bw[4+kt], ab, 0,0,0);
      else        aa = MFMA_BF16(af, bw[4+kt], aa, 0,0,0);
    }
    float* ob = out + (size_t)(m0 + 16*mt + 4*q)*128 + col;
    ob[0]   = aa.x + ab.x;
    ob[128] = aa.y + ab.y;
    ob[256] = aa.z + ab.z;
    ob[384] = aa.w + ab.w;
  }
}

extern "C" void kernel_launch(void* const* d_in, const int* in_sizes, int n_in,
                              void* d_out, int out_size, void* d_ws, size_t ws_size,
                              hipStream_t stream){
  const float* x    = (const float*)d_in[0];
  const float* Wx   = (const float*)d_in[1];
  const float* bx   = (const float*)d_in[2];
  const float* encW = (const float*)d_in[3];
  const float* encb = (const float*)d_in[4];
  const float* Wqm  = (const float*)d_in[5];
  const float* bqm  = (const float*)d_in[6];
  const float* Wz   = (const float*)d_in[7];
  const float* bz   = (const float*)d_in[8];
  const float* decW = (const float*)d_in[9];
  const float* decb = (const float*)d_in[10];
  const float* Wpm  = (const float*)d_in[11];
  const float* bpm  = (const float*)d_in[12];
  const float* Wih  = (const float*)d_in[13];
  const float* Whh  = (const float*)d_in[14];
  const float* bih  = (const float*)d_in[15];
  const float* bhh  = (const float*)d_in[16];
  const float* h0   = (const float*)d_in[17];

  float* ws = (float*)d_ws;
  size_t off = 0;
  auto alloc = [&](size_t n){ float* p = ws + off; off += n; return p; };
  float* T1  = alloc(24576);  float* T2  = alloc(49152);  float* c0a = alloc(192);
  float* A   = alloc(49152);  float* Bm  = alloc(98304);  float* c0  = alloc(384);
  float* P   = alloc(98304);  float* Q   = alloc(196608); float* r   = alloc(768);
  float* D1  = alloc(49152);  float* E1  = alloc(98304);  float* m0a = alloc(384);
  float* R   = alloc(98304);  float* r0  = alloc(768);
  float* M1  = alloc(49152);  float* M2  = alloc(98304);  float* m0  = alloc(384);
  float* Nn  = alloc(49152);  float* n0  = alloc(384);
  // Hs: 39,321,600 bf16 elements = 19,660,800 float slots (full size).
  unsigned short* Hs = (unsigned short*)(ws + off); off += 19660800;
  // U (bf16, 78.64 MB, TRANSPOSED [ct][col][512]) lives in d_out (exact fit);
  // consumed by kernB5 before kernC3 overwrites d_out with the final result.
  unsigned short* U  = (unsigned short*)d_out;

  hipLaunchKernelGGL(pre1, dim3(289),  dim3(256), 0, stream, encW, encb, Wqm, bqm, T1, T2, c0a);
  hipLaunchKernelGGL(pre2, dim3(578),  dim3(256), 0, stream, T1, T2, c0a, Wz, bz, A, Bm, c0);
  hipLaunchKernelGGL(pre3, dim3(1733), dim3(256), 0, stream, A, Bm, c0, Wih, Whh, bih, bhh,
                     decW, decb, P, Q, r, D1, E1, m0a);
  hipLaunchKernelGGL(pre4, dim3(965),  dim3(256), 0, stream, Wx, bx, P, r, D1, E1, m0a,
                     Wpm, bpm, R, r0, M1, M2, m0);
  hipLaunchKernelGGL(pre5, dim3(194),  dim3(256), 0, stream, Wx, bx, M1, m0, Nn, n0);
  hipLaunchKernelGGL(kernU2, dim3(1200), dim3(512), 0, stream, x, R, r0, U);
  hipLaunchKernelGGL(kernB5, dim3(96),   dim3(512), 0, stream, U, Q, h0, Hs);
  hipLaunchKernelGGL(kernC3, dim3(1200), dim3(512), 0, stream, x, Hs, Nn, M2, n0, (float*)d_out);
}

// Round 6
// 751.007 us; speedup vs baseline: 1.0145x; 1.0145x over previous
//
#include <hip/hip_runtime.h>
#include <hip/hip_bf16.h>
#include <cstdint>

// MCRNNVAE eval forward, algebraically collapsed:
//   h_{t+1} = tanh(x_t@R_c + r0_c + h_t@Q_c)
//   mu_t    = x_t@N_c + h_t@M2_c + n0_c
// R,Q,N,M2,r0,n0 precomputed from the raw weights (exact linear algebra).
// Round 10: kernB6 = kernB4 (row-major U, proven coalesced) + kernB5's proven
// interleaved hi/lo LDS plane (hI[2][16][257] u32 = hi|lo<<16; conflicts
// 4.9M -> 1.2M measured) with v_perm repack on read and 8x ds_write_b32
// writeback. kernU2 reverted to proven row-major-U version (round-5's
// transposed U was 8x fetch amplification: lanes strided 1KiB -> FETCH 157MB).

typedef __attribute__((ext_vector_type(8))) short short8;
typedef __attribute__((ext_vector_type(4))) float float4v;

__device__ __forceinline__ float bf2f(unsigned short u){
  union { unsigned int i; float f; } v; v.i = ((unsigned int)u) << 16; return v.f;
}
__device__ __forceinline__ unsigned short f2bf(float f){
  union { float f; unsigned int i; } v; v.f = f;
  unsigned int r = v.i + 0x7fffu + ((v.i >> 16) & 1u);
  return (unsigned short)(r >> 16);
}
__device__ __forceinline__ void st_bf2(unsigned short* p, float a, float b){
  unsigned int pa = f2bf(a), pb = f2bf(b);
  *(unsigned int*)p = pa | (pb << 16);
}
__device__ __forceinline__ float ftanh(float x){
  x = fminf(15.f, fmaxf(-15.f, x));
  float e = __expf(2.f * x);
  return (e - 1.f) * __builtin_amdgcn_rcpf(e + 1.f);
}

__device__ __forceinline__ float dotSB(const float* __restrict__ a,
                                       const float* __restrict__ b, int K, int ldb){
  float s = 0.f;
  #pragma unroll 4
  for (int k = 0; k < K; ++k) s = fmaf(a[k], b[(size_t)k * ldb], s);
  return s;
}

// ---- precompute stage 1: T1 = We1@Wqm, T2 = We2@Wqm, c0a = be@Wqm + bqm
__global__ void pre1(const float* __restrict__ encW, const float* __restrict__ encb,
                     const float* __restrict__ Wqm, const float* __restrict__ bqm,
                     float* __restrict__ T1, float* __restrict__ T2, float* __restrict__ c0a){
  int i = blockIdx.x * 256 + threadIdx.x;
  if (i < 24576){
    int c = i >> 13, rr = (i >> 6) & 127, l = i & 63;
    T1[i] = dotSB(encW + ((size_t)c*384 + rr)*128, Wqm + (size_t)c*8192 + l, 128, 64);
  } else if (i < 73728){
    int j = i - 24576; int c = j >> 14, rr = (j >> 6) & 255, l = j & 63;
    T2[j] = dotSB(encW + ((size_t)c*384 + 128 + rr)*128, Wqm + (size_t)c*8192 + l, 128, 64);
  } else if (i < 73920){
    int j = i - 73728; int c = j >> 6, l = j & 63;
    c0a[j] = dotSB(encb + c*128, Wqm + (size_t)c*8192 + l, 128, 64) + bqm[j];
  }
}

// ---- stage 2: A = T1@Wz, Bm = T2@Wz, c0 = c0a@Wz + bz
__global__ void pre2(const float* __restrict__ T1, const float* __restrict__ T2,
                     const float* __restrict__ c0a, const float* __restrict__ Wz,
                     const float* __restrict__ bz,
                     float* __restrict__ A, float* __restrict__ Bm, float* __restrict__ c0){
  int i = blockIdx.x * 256 + threadIdx.x;
  if (i < 49152){
    int c = i >> 14, rr = (i >> 7) & 127, n = i & 127;
    A[i] = dotSB(T1 + ((size_t)c*128 + rr)*64, Wz + n, 64, 128);
  } else if (i < 147456){
    int j = i - 49152; int c = j >> 15, rr = (j >> 7) & 255, n = j & 127;
    Bm[j] = dotSB(T2 + ((size_t)c*256 + rr)*64, Wz + n, 64, 128);
  } else if (i < 147840){
    int j = i - 147456; int c = j >> 7, n = j & 127;
    c0[j] = dotSB(c0a + c*64, Wz + n, 64, 128) + bz[n];
  }
}

// ---- stage 3: P = Wi1 + A@Wi2; Q = Whh + Bm@Wi2; r = c0@Wi2 + bih + bhh;
//               D1 = A@Wd1; E1 = Wd2 + Bm@Wd1; m0a = c0@Wd1 + bd
__global__ void pre3(const float* __restrict__ A, const float* __restrict__ Bm,
                     const float* __restrict__ c0, const float* __restrict__ Wih,
                     const float* __restrict__ Whh, const float* __restrict__ bih,
                     const float* __restrict__ bhh, const float* __restrict__ decW,
                     const float* __restrict__ decb,
                     float* __restrict__ P, float* __restrict__ Q, float* __restrict__ r,
                     float* __restrict__ D1, float* __restrict__ E1, float* __restrict__ m0a){
  int i = blockIdx.x * 256 + threadIdx.x;
  const float* Wi2 = Wih + 128*256;
  if (i < 98304){
    int c = i >> 15, rr = (i >> 8) & 127, n = i & 255;
    P[i] = Wih[rr*256 + n] + dotSB(A + ((size_t)c*128 + rr)*128, Wi2 + n, 128, 256);
  } else if (i < 294912){
    int j = i - 98304; int c = j >> 16, rr = (j >> 8) & 255, n = j & 255;
    Q[j] = Whh[rr*256 + n] + dotSB(Bm + ((size_t)c*256 + rr)*128, Wi2 + n, 128, 256);
  } else if (i < 295680){
    int j = i - 294912; int c = j >> 8, n = j & 255;
    r[j] = dotSB(c0 + c*128, Wi2 + n, 128, 256) + bih[n] + bhh[n];
  } else if (i < 344832){
    int j = i - 295680; int c = j >> 14, rr = (j >> 7) & 127, n = j & 127;
    D1[j] = dotSB(A + ((size_t)c*128 + rr)*128, decW + (size_t)c*49152 + n, 128, 128);
  } else if (i < 443136){
    int j = i - 344832; int c = j >> 15, rr = (j >> 7) & 255, n = j & 127;
    E1[j] = decW[(size_t)c*49152 + (size_t)(128 + rr)*128 + n]
          + dotSB(Bm + ((size_t)c*256 + rr)*128, decW + (size_t)c*49152 + n, 128, 128);
  } else if (i < 443520){
    int j = i - 443136; int c = j >> 7, n = j & 127;
    m0a[j] = dotSB(c0 + c*128, decW + (size_t)c*49152 + n, 128, 128) + decb[j];
  }
}

// ---- stage 4: R = Wx@P; r0 = bx@P + r; M1 = D1@Wpm; M2 = E1@Wpm; m0 = m0a@Wpm + bpm
__global__ void pre4(const float* __restrict__ Wx, const float* __restrict__ bx,
                     const float* __restrict__ P, const float* __restrict__ r,
                     const float* __restrict__ D1, const float* __restrict__ E1,
                     const float* __restrict__ m0a, const float* __restrict__ Wpm,
                     const float* __restrict__ bpm,
                     float* __restrict__ R, float* __restrict__ r0,
                     float* __restrict__ M1, float* __restrict__ M2, float* __restrict__ m0){
  int i = blockIdx.x * 256 + threadIdx.x;
  if (i < 98304){
    int c = i >> 15, rr = (i >> 8) & 127, n = i & 255;
    R[i] = dotSB(Wx + ((size_t)c*128 + rr)*128, P + (size_t)c*32768 + n, 128, 256);
  } else if (i < 99072){
    int j = i - 98304; int c = j >> 8, n = j & 255;
    r0[j] = dotSB(bx + c*128, P + (size_t)c*32768 + n, 128, 256) + r[j];
  } else if (i < 148224){
    int j = i - 99072; int c = j >> 14, rr = (j >> 7) & 127, n = j & 127;
    M1[j] = dotSB(D1 + ((size_t)c*128 + rr)*128, Wpm + (size_t)c*16384 + n, 128, 128);
  } else if (i < 246528){
    int j = i - 148224; int c = j >> 15, rr = (j >> 7) & 255, n = j & 127;
    M2[j] = dotSB(E1 + ((size_t)c*256 + rr)*128, Wpm + (size_t)c*16384 + n, 128, 128);
  } else if (i < 246912){
    int j = i - 246528; int c = j >> 7, n = j & 127;
    m0[j] = dotSB(m0a + c*128, Wpm + (size_t)c*16384 + n, 128, 128) + bpm[j];
  }
}

// ---- stage 5: Nn = Wx@M1; n0 = bx@M1 + m0
__global__ void pre5(const float* __restrict__ Wx, const float* __restrict__ bx,
                     const float* __restrict__ M1, const float* __restrict__ m0,
                     float* __restrict__ Nn, float* __restrict__ n0){
  int i = blockIdx.x * 256 + threadIdx.x;
  if (i < 49152){
    int c = i >> 14, rr = (i >> 7) & 127, n = i & 127;
    Nn[i] = dotSB(Wx + ((size_t)c*128 + rr)*128, M1 + (size_t)c*16384 + n, 128, 128);
  } else if (i < 49536){
    int j = i - 49152; int c = j >> 7, n = j & 127;
    n0[j] = dotSB(bx + c*128, M1 + (size_t)c*16384 + n, 128, 128) + m0[j];
  }
}

#define MFMA_BF16 __builtin_amdgcn_mfma_f32_16x16x32_bf16

// ---- kernU2: U = x@R + r0 (bf16, ROW-MAJOR) via MFMA. 1200 blocks x 512 thr.
// (proven round-0/3 version — coalesced stores, lanes m consecutive)
__global__ __launch_bounds__(512, 2)
void kernU2(const float* __restrict__ x, const float* __restrict__ Rg,
            const float* __restrict__ r0g, unsigned short* __restrict__ U){
  __shared__ unsigned short xs[128][136];
  const int m0 = blockIdx.x * 128;
  const int c  = m0 / 51200;                   // 400 blocks/channel, no straddle
  const int w  = threadIdx.x >> 6;
  const int l  = threadIdx.x & 63;
  const int q  = l >> 4, m = l & 15;
  const float* __restrict__ Rc = Rg + (size_t)c * 32768;   // [128][256]

  short8 rf[4][2];
  #pragma unroll
  for (int kt = 0; kt < 4; ++kt)
    #pragma unroll
    for (int nt = 0; nt < 2; ++nt){
      union { short8 v; unsigned short u[8]; } tmp;
      const int col = 32*w + 16*nt + m;
      #pragma unroll
      for (int j = 0; j < 8; ++j)
        tmp.u[j] = f2bf(Rc[(size_t)(32*kt + 8*q + j)*256 + col]);
      rf[kt][nt] = tmp.v;
    }
  const float r0v0 = r0g[c*256 + 32*w + m];
  const float r0v1 = r0g[c*256 + 32*w + 16 + m];

  {
    const int r  = threadIdx.x >> 2;
    const int c0 = (threadIdx.x & 3) * 32;
    const float* xr = x + (size_t)(m0 + r)*128 + c0;
    #pragma unroll
    for (int i = 0; i < 8; ++i){
      float4 v = *(const float4*)(xr + 4*i);
      st_bf2(&xs[r][c0 + 4*i],     v.x, v.y);
      st_bf2(&xs[r][c0 + 4*i + 2], v.z, v.w);
    }
  }
  __syncthreads();

  #pragma unroll 1
  for (int mt = 0; mt < 8; ++mt){
    float4v a0 = { r0v0, r0v0, r0v0, r0v0 };
    float4v a1 = { r0v1, r0v1, r0v1, r0v1 };
    #pragma unroll
    for (int kt = 0; kt < 4; ++kt){
      short8 af = *(const short8*)&xs[16*mt + m][32*kt + 8*q];
      a0 = MFMA_BF16(af, rf[kt][0], a0, 0,0,0);
      a1 = MFMA_BF16(af, rf[kt][1], a1, 0,0,0);
    }
    unsigned short* ub = U + (size_t)(m0 + 16*mt + 4*q)*256;
    ub[0*256 + 32*w + m]      = f2bf(a0.x);
    ub[1*256 + 32*w + m]      = f2bf(a0.y);
    ub[2*256 + 32*w + m]      = f2bf(a0.z);
    ub[3*256 + 32*w + m]      = f2bf(a0.w);
    ub[0*256 + 32*w + 16 + m] = f2bf(a1.x);
    ub[1*256 + 32*w + 16 + m] = f2bf(a1.y);
    ub[2*256 + 32*w + 16 + m] = f2bf(a1.z);
    ub[3*256 + 32*w + 16 + m] = f2bf(a1.w);
  }
}

// ---- kernB6: recurrence h_{t+1} = tanh(U_t + h_t@Q_c) via MFMA.
// 96 blocks x 512 thr (8 waves). Row-major U (coalesced, proven kernB4) +
// interleaved hi/lo LDS plane hI[2][16][257] (proven kernB5: conflicts 4x down;
// u32 = hi|lo<<16 per col; stride 257 dw == 1 mod 32 -> banks (m+8q)%32 = 2-way
// free). 8 ds_write_b32 writeback, v_perm repack on b128 reads, single
// barrier/step, 4 independent acc chains.
__global__ __launch_bounds__(512, 2)
void kernB6(const unsigned short* __restrict__ U, const float* __restrict__ Qg,
            const float* __restrict__ h0, unsigned short* __restrict__ Hs){
  __shared__ unsigned int hI[2][16][257];      // col 0..255 + bank-spread pad
  const int c  = blockIdx.x >> 5;
  const int b0 = (blockIdx.x & 31) << 4;
  const int w  = threadIdx.x >> 6;
  const int l  = threadIdx.x & 63;
  const int q  = l >> 4, m = l & 15;
  const float* __restrict__ Qc = Qg + (size_t)c * 65536;

  short8 qf[8][2];
  #pragma unroll
  for (int kt = 0; kt < 8; ++kt)
    #pragma unroll
    for (int nt = 0; nt < 2; ++nt){
      union { short8 v; unsigned short u[8]; } tmp;
      const int col = 32*w + 16*nt + m;
      #pragma unroll
      for (int j = 0; j < 8; ++j)
        tmp.u[j] = f2bf(Qc[(size_t)(32*kt + 8*q + j)*256 + col]);
      qf[kt][nt] = tmp.v;
    }

  unsigned short hiR[8];
  #pragma unroll
  for (int nt = 0; nt < 2; ++nt){
    const int col = 32*w + 16*nt + m;
    #pragma unroll
    for (int r = 0; r < 4; ++r){
      const int row = 4*q + r;
      float v = h0[((size_t)c*512 + b0 + row)*256 + col];
      unsigned short hi = f2bf(v);
      hiR[nt*4 + r] = hi;
      hI[0][row][col] = (unsigned int)hi | ((unsigned int)f2bf(v - bf2f(hi)) << 16);
    }
  }
  __syncthreads();

  unsigned short un[8];
  #pragma unroll
  for (int nt = 0; nt < 2; ++nt)
    #pragma unroll
    for (int r = 0; r < 4; ++r)
      un[nt*4 + r] = U[((size_t)(c*100 + 0)*512 + b0 + 4*q + r)*256 + 32*w + 16*nt + m];

  #pragma unroll 1
  for (int t = 0; t < 100; ++t){
    const int cur = t & 1, nxt = cur ^ 1;

    // store h_t (bf16) to Hs — fire-and-forget
    const size_t rowbase = (size_t)(c*100 + t)*512 + b0;
    #pragma unroll
    for (int nt = 0; nt < 2; ++nt)
      #pragma unroll
      for (int r = 0; r < 4; ++r)
        Hs[(rowbase + 4*q + r)*256 + 32*w + 16*nt + m] = hiR[nt*4 + r];

    // acc chains: hi seeded with U_t, lo zero (summed before tanh)
    float4v a0h = { bf2f(un[0]), bf2f(un[1]), bf2f(un[2]), bf2f(un[3]) };
    float4v a1h = { bf2f(un[4]), bf2f(un[5]), bf2f(un[6]), bf2f(un[7]) };
    float4v a0l = { 0.f, 0.f, 0.f, 0.f };
    float4v a1l = { 0.f, 0.f, 0.f, 0.f };

    // prefetch U_{t+1} (row-major, coalesced; retires by next-step use)
    const int tn = (t < 99) ? t + 1 : 99;
    unsigned short unN[8];
    #pragma unroll
    for (int nt = 0; nt < 2; ++nt)
      #pragma unroll
      for (int r = 0; r < 4; ++r)
        unN[nt*4 + r] = U[((size_t)(c*100 + tn)*512 + b0 + 4*q + r)*256 + 32*w + 16*nt + m];

    const unsigned int* hrow = &hI[cur][m][0];
    #pragma unroll
    for (int kt = 0; kt < 8; ++kt){
      uint4 u0 = *(const uint4*)(hrow + 32*kt + 8*q);
      uint4 u1 = *(const uint4*)(hrow + 32*kt + 8*q + 4);
      union { short8 v; unsigned int d[4]; } ahi, alo;
      ahi.d[0] = __builtin_amdgcn_perm(u0.y, u0.x, 0x05040100u);
      ahi.d[1] = __builtin_amdgcn_perm(u0.w, u0.z, 0x05040100u);
      ahi.d[2] = __builtin_amdgcn_perm(u1.y, u1.x, 0x05040100u);
      ahi.d[3] = __builtin_amdgcn_perm(u1.w, u1.z, 0x05040100u);
      alo.d[0] = __builtin_amdgcn_perm(u0.y, u0.x, 0x07060302u);
      alo.d[1] = __builtin_amdgcn_perm(u0.w, u0.z, 0x07060302u);
      alo.d[2] = __builtin_amdgcn_perm(u1.y, u1.x, 0x07060302u);
      alo.d[3] = __builtin_amdgcn_perm(u1.w, u1.z, 0x07060302u);
      a0h = MFMA_BF16(ahi.v, qf[kt][0], a0h, 0,0,0);
      a1h = MFMA_BF16(ahi.v, qf[kt][1], a1h, 0,0,0);
      a0l = MFMA_BF16(alo.v, qf[kt][0], a0l, 0,0,0);
      a1l = MFMA_BF16(alo.v, qf[kt][1], a1l, 0,0,0);
    }

    float hn[8];
    hn[0] = ftanh(a0h.x + a0l.x); hn[1] = ftanh(a0h.y + a0l.y);
    hn[2] = ftanh(a0h.z + a0l.z); hn[3] = ftanh(a0h.w + a0l.w);
    hn[4] = ftanh(a1h.x + a1l.x); hn[5] = ftanh(a1h.y + a1l.y);
    hn[6] = ftanh(a1h.z + a1l.z); hn[7] = ftanh(a1h.w + a1l.w);

    // write h_{t+1} into NEXT buffer as packed hi|lo (8 x ds_write_b32)
    #pragma unroll
    for (int nt = 0; nt < 2; ++nt){
      const int col = 32*w + 16*nt + m;
      #pragma unroll
      for (int r = 0; r < 4; ++r){
        const int row = 4*q + r;
        float v = hn[nt*4 + r];
        unsigned short hi = f2bf(v);
        hiR[nt*4 + r] = hi;
        hI[nxt][row][col] = (unsigned int)hi | ((unsigned int)f2bf(v - bf2f(hi)) << 16);
      }
    }
    #pragma unroll
    for (int i = 0; i < 8; ++i) un[i] = unN[i];

    __syncthreads();   // single barrier per step
  }
}

// ---- kernC3: out = x@Nn + Hs@M2 + n0 via MFMA. 1200 blocks x 512 thr. (proven)
__global__ __launch_bounds__(512, 2)
void kernC3(const float* __restrict__ x, const unsigned short* __restrict__ Hs,
            const float* __restrict__ Nn, const float* __restrict__ M2,
            const float* __restrict__ n0, float* __restrict__ out){
  __shared__ unsigned short xs[128][136];
  const int m0 = blockIdx.x * 128;
  const int c  = m0 / 51200;
  const int w  = threadIdx.x >> 6;
  const int l  = threadIdx.x & 63;
  const int q  = l >> 4, m = l & 15;
  const int col = 16*w + m;
  const float* __restrict__ Nc  = Nn + (size_t)c * 16384;   // [128][128]
  const float* __restrict__ M2c = M2 + (size_t)c * 32768;   // [256][128]

  short8 bw[12];
  #pragma unroll
  for (int kt = 0; kt < 4; ++kt){
    union { short8 v; unsigned short u[8]; } tmp;
    #pragma unroll
    for (int j = 0; j < 8; ++j)
      tmp.u[j] = f2bf(Nc[(size_t)(32*kt + 8*q + j)*128 + col]);
    bw[kt] = tmp.v;
  }
  #pragma unroll
  for (int kt = 0; kt < 8; ++kt){
    union { short8 v; unsigned short u[8]; } tmp;
    #pragma unroll
    for (int j = 0; j < 8; ++j)
      tmp.u[j] = f2bf(M2c[(size_t)(32*kt + 8*q + j)*128 + col]);
    bw[4 + kt] = tmp.v;
  }
  const float nz = n0[c*128 + col];

  {
    const int r  = threadIdx.x >> 2;
    const int c0 = (threadIdx.x & 3) * 32;
    const float* xr = x + (size_t)(m0 + r)*128 + c0;
    #pragma unroll
    for (int i = 0; i < 8; ++i){
      float4 v = *(const float4*)(xr + 4*i);
      st_bf2(&xs[r][c0 + 4*i],     v.x, v.y);
      st_bf2(&xs[r][c0 + 4*i + 2], v.z, v.w);
    }
  }
  __syncthreads();

  #pragma unroll 1
  for (int mt = 0; mt < 8; ++mt){
    float4v aa = { nz, nz, nz, nz }, ab = { 0.f, 0.f, 0.f, 0.f };
    #pragma unroll
    for (int kt = 0; kt < 4; ++kt){
      short8 af = *(const short8*)&xs[16*mt + m][32*kt + 8*q];
      if (kt & 1) ab = MFMA_BF16(af, bw[kt], ab, 0,0,0);
      else        aa = MFMA_BF16(af, bw[kt], aa, 0,0,0);
    }
    const size_t mrow = (size_t)(m0 + 16*mt) + m;
    #pragma unroll
    for (int kt = 0; kt < 8; ++kt){
      short8 af = *(const short8*)&Hs[mrow*256 + 32*kt + 8*q];
      if (kt & 1) ab = MFMA_BF16(af, bw[4+kt], ab, 0,0,0);
      else        aa = MFMA_BF16(af, bw[4+kt], aa, 0,0,0);
    }
    float* ob = out + (size_t)(m0 + 16*mt + 4*q)*128 + col;
    ob[0]   = aa.x + ab.x;
    ob[128] = aa.y + ab.y;
    ob[256] = aa.z + ab.z;
    ob[384] = aa.w + ab.w;
  }
}

extern "C" void kernel_launch(void* const* d_in, const int* in_sizes, int n_in,
                              void* d_out, int out_size, void* d_ws, size_t ws_size,
                              hipStream_t stream){
  const float* x    = (const float*)d_in[0];
  const float* Wx   = (const float*)d_in[1];
  const float* bx   = (const float*)d_in[2];
  const float* encW = (const float*)d_in[3];
  const float* encb = (const float*)d_in[4];
  const float* Wqm  = (const float*)d_in[5];
  const float* bqm  = (const float*)d_in[6];
  const float* Wz   = (const float*)d_in[7];
  const float* bz   = (const float*)d_in[8];
  const float* decW = (const float*)d_in[9];
  const float* decb = (const float*)d_in[10];
  const float* Wpm  = (const float*)d_in[11];
  const float* bpm  = (const float*)d_in[12];
  const float* Wih  = (const float*)d_in[13];
  const float* Whh  = (const float*)d_in[14];
  const float* bih  = (const float*)d_in[15];
  const float* bhh  = (const float*)d_in[16];
  const float* h0   = (const float*)d_in[17];

  float* ws = (float*)d_ws;
  size_t off = 0;
  auto alloc = [&](size_t n){ float* p = ws + off; off += n; return p; };
  float* T1  = alloc(24576);  float* T2  = alloc(49152);  float* c0a = alloc(192);
  float* A   = alloc(49152);  float* Bm  = alloc(98304);  float* c0  = alloc(384);
  float* P   = alloc(98304);  float* Q   = alloc(196608); float* r   = alloc(768);
  float* D1  = alloc(49152);  float* E1  = alloc(98304);  float* m0a = alloc(384);
  float* R   = alloc(98304);  float* r0  = alloc(768);
  float* M1  = alloc(49152);  float* M2  = alloc(98304);  float* m0  = alloc(384);
  float* Nn  = alloc(49152);  float* n0  = alloc(384);
  // Hs: 39,321,600 bf16 elements = 19,660,800 float slots (full size).
  unsigned short* Hs = (unsigned short*)(ws + off); off += 19660800;
  // U (bf16, 78.64 MB, ROW-MAJOR) lives in d_out (exact fit); consumed by
  // kernB6 before kernC3 overwrites d_out with the final result.
  unsigned short* U  = (unsigned short*)d_out;

  hipLaunchKernelGGL(pre1, dim3(289),  dim3(256), 0, stream, encW, encb, Wqm, bqm, T1, T2, c0a);
  hipLaunchKernelGGL(pre2, dim3(578),  dim3(256), 0, stream, T1, T2, c0a, Wz, bz, A, Bm, c0);
  hipLaunchKernelGGL(pre3, dim3(1733), dim3(256), 0, stream, A, Bm, c0, Wih, Whh, bih, bhh,
                     decW, decb, P, Q, r, D1, E1, m0a);
  hipLaunchKernelGGL(pre4, dim3(965),  dim3(256), 0, stream, Wx, bx, P, r, D1, E1, m0a,
                     Wpm, bpm, R, r0, M1, M2, m0);
  hipLaunchKernelGGL(pre5, dim3(194),  dim3(256), 0, stream, Wx, bx, M1, m0, Nn, n0);
  hipLaunchKernelGGL(kernU2, dim3(1200), dim3(512), 0, stream, x, R, r0, U);
  hipLaunchKernelGGL(kernB6, dim3(96),   dim3(512), 0, stream, U, Q, h0, Hs);
  hipLaunchKernelGGL(kernC3, dim3(1200), dim3(512), 0, stream, x, Hs, Nn, M2, n0, (float*)d_out);
}

// Round 8
// 492.000 us; speedup vs baseline: 1.5486x; 1.5264x over previous
//
#include <hip/hip_runtime.h>
#include <hip/hip_bf16.h>
#include <cstdint>

// MCRNNVAE eval forward, algebraically collapsed:
//   h_{t+1} = tanh(x_t@R_c + r0_c + h_t@Q_c)
//   mu_t    = x_t@N_c + h_t@M2_c + n0_c
// R,Q,N,M2,r0,n0 precomputed from the raw weights (exact linear algebra).
// Round 12 (= round 11 resubmitted; infra failure, no result): kernB7 = kernB6
// with ONE change: hI row stride 257 -> 260 dwords. 257 dw = 1028 B is not
// 16B-aligned -> every uint4 LDS read was split into scalar ds_read_b32 (the
// 3x stall in rounds 5/6: MfmaUtil 11.6->3.9 with LOW conflicts). 260 dw =
// 1040 B: all read addrs (m*260+32kt+8q)*4 are 16B multiples -> true
// ds_read_b128; bank-quad distribution (m+2q)%8 uniform 8 lanes/quad =
// conflict-free optimum. Writes 2-way (free). LDS size same (33 KB).

typedef __attribute__((ext_vector_type(8))) short short8;
typedef __attribute__((ext_vector_type(4))) float float4v;

__device__ __forceinline__ float bf2f(unsigned short u){
  union { unsigned int i; float f; } v; v.i = ((unsigned int)u) << 16; return v.f;
}
__device__ __forceinline__ unsigned short f2bf(float f){
  union { float f; unsigned int i; } v; v.f = f;
  unsigned int r = v.i + 0x7fffu + ((v.i >> 16) & 1u);
  return (unsigned short)(r >> 16);
}
__device__ __forceinline__ void st_bf2(unsigned short* p, float a, float b){
  unsigned int pa = f2bf(a), pb = f2bf(b);
  *(unsigned int*)p = pa | (pb << 16);
}
__device__ __forceinline__ float ftanh(float x){
  x = fminf(15.f, fmaxf(-15.f, x));
  float e = __expf(2.f * x);
  return (e - 1.f) * __builtin_amdgcn_rcpf(e + 1.f);
}

__device__ __forceinline__ float dotSB(const float* __restrict__ a,
                                       const float* __restrict__ b, int K, int ldb){
  float s = 0.f;
  #pragma unroll 4
  for (int k = 0; k < K; ++k) s = fmaf(a[k], b[(size_t)k * ldb], s);
  return s;
}

// ---- precompute stage 1: T1 = We1@Wqm, T2 = We2@Wqm, c0a = be@Wqm + bqm
__global__ void pre1(const float* __restrict__ encW, const float* __restrict__ encb,
                     const float* __restrict__ Wqm, const float* __restrict__ bqm,
                     float* __restrict__ T1, float* __restrict__ T2, float* __restrict__ c0a){
  int i = blockIdx.x * 256 + threadIdx.x;
  if (i < 24576){
    int c = i >> 13, rr = (i >> 6) & 127, l = i & 63;
    T1[i] = dotSB(encW + ((size_t)c*384 + rr)*128, Wqm + (size_t)c*8192 + l, 128, 64);
  } else if (i < 73728){
    int j = i - 24576; int c = j >> 14, rr = (j >> 6) & 255, l = j & 63;
    T2[j] = dotSB(encW + ((size_t)c*384 + 128 + rr)*128, Wqm + (size_t)c*8192 + l, 128, 64);
  } else if (i < 73920){
    int j = i - 73728; int c = j >> 6, l = j & 63;
    c0a[j] = dotSB(encb + c*128, Wqm + (size_t)c*8192 + l, 128, 64) + bqm[j];
  }
}

// ---- stage 2: A = T1@Wz, Bm = T2@Wz, c0 = c0a@Wz + bz
__global__ void pre2(const float* __restrict__ T1, const float* __restrict__ T2,
                     const float* __restrict__ c0a, const float* __restrict__ Wz,
                     const float* __restrict__ bz,
                     float* __restrict__ A, float* __restrict__ Bm, float* __restrict__ c0){
  int i = blockIdx.x * 256 + threadIdx.x;
  if (i < 49152){
    int c = i >> 14, rr = (i >> 7) & 127, n = i & 127;
    A[i] = dotSB(T1 + ((size_t)c*128 + rr)*64, Wz + n, 64, 128);
  } else if (i < 147456){
    int j = i - 49152; int c = j >> 15, rr = (j >> 7) & 255, n = j & 127;
    Bm[j] = dotSB(T2 + ((size_t)c*256 + rr)*64, Wz + n, 64, 128);
  } else if (i < 147840){
    int j = i - 147456; int c = j >> 7, n = j & 127;
    c0[j] = dotSB(c0a + c*64, Wz + n, 64, 128) + bz[n];
  }
}

// ---- stage 3: P = Wi1 + A@Wi2; Q = Whh + Bm@Wi2; r = c0@Wi2 + bih + bhh;
//               D1 = A@Wd1; E1 = Wd2 + Bm@Wd1; m0a = c0@Wd1 + bd
__global__ void pre3(const float* __restrict__ A, const float* __restrict__ Bm,
                     const float* __restrict__ c0, const float* __restrict__ Wih,
                     const float* __restrict__ Whh, const float* __restrict__ bih,
                     const float* __restrict__ bhh, const float* __restrict__ decW,
                     const float* __restrict__ decb,
                     float* __restrict__ P, float* __restrict__ Q, float* __restrict__ r,
                     float* __restrict__ D1, float* __restrict__ E1, float* __restrict__ m0a){
  int i = blockIdx.x * 256 + threadIdx.x;
  const float* Wi2 = Wih + 128*256;
  if (i < 98304){
    int c = i >> 15, rr = (i >> 8) & 127, n = i & 255;
    P[i] = Wih[rr*256 + n] + dotSB(A + ((size_t)c*128 + rr)*128, Wi2 + n, 128, 256);
  } else if (i < 294912){
    int j = i - 98304; int c = j >> 16, rr = (j >> 8) & 255, n = j & 255;
    Q[j] = Whh[rr*256 + n] + dotSB(Bm + ((size_t)c*256 + rr)*128, Wi2 + n, 128, 256);
  } else if (i < 295680){
    int j = i - 294912; int c = j >> 8, n = j & 255;
    r[j] = dotSB(c0 + c*128, Wi2 + n, 128, 256) + bih[n] + bhh[n];
  } else if (i < 344832){
    int j = i - 295680; int c = j >> 14, rr = (j >> 7) & 127, n = j & 127;
    D1[j] = dotSB(A + ((size_t)c*128 + rr)*128, decW + (size_t)c*49152 + n, 128, 128);
  } else if (i < 443136){
    int j = i - 344832; int c = j >> 15, rr = (j >> 7) & 255, n = j & 127;
    E1[j] = decW[(size_t)c*49152 + (size_t)(128 + rr)*128 + n]
          + dotSB(Bm + ((size_t)c*256 + rr)*128, decW + (size_t)c*49152 + n, 128, 128);
  } else if (i < 443520){
    int j = i - 443136; int c = j >> 7, n = j & 127;
    m0a[j] = dotSB(c0 + c*128, decW + (size_t)c*49152 + n, 128, 128) + decb[j];
  }
}

// ---- stage 4: R = Wx@P; r0 = bx@P + r; M1 = D1@Wpm; M2 = E1@Wpm; m0 = m0a@Wpm + bpm
__global__ void pre4(const float* __restrict__ Wx, const float* __restrict__ bx,
                     const float* __restrict__ P, const float* __restrict__ r,
                     const float* __restrict__ D1, const float* __restrict__ E1,
                     const float* __restrict__ m0a, const float* __restrict__ Wpm,
                     const float* __restrict__ bpm,
                     float* __restrict__ R, float* __restrict__ r0,
                     float* __restrict__ M1, float* __restrict__ M2, float* __restrict__ m0){
  int i = blockIdx.x * 256 + threadIdx.x;
  if (i < 98304){
    int c = i >> 15, rr = (i >> 8) & 127, n = i & 255;
    R[i] = dotSB(Wx + ((size_t)c*128 + rr)*128, P + (size_t)c*32768 + n, 128, 256);
  } else if (i < 99072){
    int j = i - 98304; int c = j >> 8, n = j & 255;
    r0[j] = dotSB(bx + c*128, P + (size_t)c*32768 + n, 128, 256) + r[j];
  } else if (i < 148224){
    int j = i - 99072; int c = j >> 14, rr = (j >> 7) & 127, n = j & 127;
    M1[j] = dotSB(D1 + ((size_t)c*128 + rr)*128, Wpm + (size_t)c*16384 + n, 128, 128);
  } else if (i < 246528){
    int j = i - 148224; int c = j >> 15, rr = (j >> 7) & 255, n = j & 127;
    M2[j] = dotSB(E1 + ((size_t)c*256 + rr)*128, Wpm + (size_t)c*16384 + n, 128, 128);
  } else if (i < 246912){
    int j = i - 246528; int c = j >> 7, n = j & 127;
    m0[j] = dotSB(m0a + c*128, Wpm + (size_t)c*16384 + n, 128, 128) + bpm[j];
  }
}

// ---- stage 5: Nn = Wx@M1; n0 = bx@M1 + m0
__global__ void pre5(const float* __restrict__ Wx, const float* __restrict__ bx,
                     const float* __restrict__ M1, const float* __restrict__ m0,
                     float* __restrict__ Nn, float* __restrict__ n0){
  int i = blockIdx.x * 256 + threadIdx.x;
  if (i < 49152){
    int c = i >> 14, rr = (i >> 7) & 127, n = i & 127;
    Nn[i] = dotSB(Wx + ((size_t)c*128 + rr)*128, M1 + (size_t)c*16384 + n, 128, 128);
  } else if (i < 49536){
    int j = i - 49152; int c = j >> 7, n = j & 127;
    n0[j] = dotSB(bx + c*128, M1 + (size_t)c*16384 + n, 128, 128) + m0[j];
  }
}

#define MFMA_BF16 __builtin_amdgcn_mfma_f32_16x16x32_bf16

// ---- kernU2: U = x@R + r0 (bf16, ROW-MAJOR) via MFMA. 1200 blocks x 512 thr.
// (proven round-0/3 version — coalesced stores, lanes m consecutive)
__global__ __launch_bounds__(512, 2)
void kernU2(const float* __restrict__ x, const float* __restrict__ Rg,
            const float* __restrict__ r0g, unsigned short* __restrict__ U){
  __shared__ unsigned short xs[128][136];
  const int m0 = blockIdx.x * 128;
  const int c  = m0 / 51200;                   // 400 blocks/channel, no straddle
  const int w  = threadIdx.x >> 6;
  const int l  = threadIdx.x & 63;
  const int q  = l >> 4, m = l & 15;
  const float* __restrict__ Rc = Rg + (size_t)c * 32768;   // [128][256]

  short8 rf[4][2];
  #pragma unroll
  for (int kt = 0; kt < 4; ++kt)
    #pragma unroll
    for (int nt = 0; nt < 2; ++nt){
      union { short8 v; unsigned short u[8]; } tmp;
      const int col = 32*w + 16*nt + m;
      #pragma unroll
      for (int j = 0; j < 8; ++j)
        tmp.u[j] = f2bf(Rc[(size_t)(32*kt + 8*q + j)*256 + col]);
      rf[kt][nt] = tmp.v;
    }
  const float r0v0 = r0g[c*256 + 32*w + m];
  const float r0v1 = r0g[c*256 + 32*w + 16 + m];

  {
    const int r  = threadIdx.x >> 2;
    const int c0 = (threadIdx.x & 3) * 32;
    const float* xr = x + (size_t)(m0 + r)*128 + c0;
    #pragma unroll
    for (int i = 0; i < 8; ++i){
      float4 v = *(const float4*)(xr + 4*i);
      st_bf2(&xs[r][c0 + 4*i],     v.x, v.y);
      st_bf2(&xs[r][c0 + 4*i + 2], v.z, v.w);
    }
  }
  __syncthreads();

  #pragma unroll 1
  for (int mt = 0; mt < 8; ++mt){
    float4v a0 = { r0v0, r0v0, r0v0, r0v0 };
    float4v a1 = { r0v1, r0v1, r0v1, r0v1 };
    #pragma unroll
    for (int kt = 0; kt < 4; ++kt){
      short8 af = *(const short8*)&xs[16*mt + m][32*kt + 8*q];
      a0 = MFMA_BF16(af, rf[kt][0], a0, 0,0,0);
      a1 = MFMA_BF16(af, rf[kt][1], a1, 0,0,0);
    }
    unsigned short* ub = U + (size_t)(m0 + 16*mt + 4*q)*256;
    ub[0*256 + 32*w + m]      = f2bf(a0.x);
    ub[1*256 + 32*w + m]      = f2bf(a0.y);
    ub[2*256 + 32*w + m]      = f2bf(a0.z);
    ub[3*256 + 32*w + m]      = f2bf(a0.w);
    ub[0*256 + 32*w + 16 + m] = f2bf(a1.x);
    ub[1*256 + 32*w + 16 + m] = f2bf(a1.y);
    ub[2*256 + 32*w + 16 + m] = f2bf(a1.z);
    ub[3*256 + 32*w + 16 + m] = f2bf(a1.w);
  }
}

// ---- kernB7: recurrence h_{t+1} = tanh(U_t + h_t@Q_c) via MFMA.
// 96 blocks x 512 thr (8 waves). Interleaved hi/lo LDS plane hI[2][16][260]
// (u32 = hi|lo<<16 per col; stride 260 dw = 1040 B -> 16B-aligned b128 reads,
// uniform 8 lanes/bank-quad = conflict-free). 8 ds_write_b32 writeback,
// v_perm repack, row-major coalesced U, single barrier/step, 4 acc chains.
__global__ __launch_bounds__(512, 2)
void kernB7(const unsigned short* __restrict__ U, const float* __restrict__ Qg,
            const float* __restrict__ h0, unsigned short* __restrict__ Hs){
  __shared__ unsigned int hI[2][16][260];      // 260 dw stride: aligned + spread
  const int c  = blockIdx.x >> 5;
  const int b0 = (blockIdx.x & 31) << 4;
  const int w  = threadIdx.x >> 6;
  const int l  = threadIdx.x & 63;
  const int q  = l >> 4, m = l & 15;
  const float* __restrict__ Qc = Qg + (size_t)c * 65536;

  short8 qf[8][2];
  #pragma unroll
  for (int kt = 0; kt < 8; ++kt)
    #pragma unroll
    for (int nt = 0; nt < 2; ++nt){
      union { short8 v; unsigned short u[8]; } tmp;
      const int col = 32*w + 16*nt + m;
      #pragma unroll
      for (int j = 0; j < 8; ++j)
        tmp.u[j] = f2bf(Qc[(size_t)(32*kt + 8*q + j)*256 + col]);
      qf[kt][nt] = tmp.v;
    }

  unsigned short hiR[8];
  #pragma unroll
  for (int nt = 0; nt < 2; ++nt){
    const int col = 32*w + 16*nt + m;
    #pragma unroll
    for (int r = 0; r < 4; ++r){
      const int row = 4*q + r;
      float v = h0[((size_t)c*512 + b0 + row)*256 + col];
      unsigned short hi = f2bf(v);
      hiR[nt*4 + r] = hi;
      hI[0][row][col] = (unsigned int)hi | ((unsigned int)f2bf(v - bf2f(hi)) << 16);
    }
  }
  __syncthreads();

  unsigned short un[8];
  #pragma unroll
  for (int nt = 0; nt < 2; ++nt)
    #pragma unroll
    for (int r = 0; r < 4; ++r)
      un[nt*4 + r] = U[((size_t)(c*100 + 0)*512 + b0 + 4*q + r)*256 + 32*w + 16*nt + m];

  #pragma unroll 1
  for (int t = 0; t < 100; ++t){
    const int cur = t & 1, nxt = cur ^ 1;

    // store h_t (bf16) to Hs — fire-and-forget
    const size_t rowbase = (size_t)(c*100 + t)*512 + b0;
    #pragma unroll
    for (int nt = 0; nt < 2; ++nt)
      #pragma unroll
      for (int r = 0; r < 4; ++r)
        Hs[(rowbase + 4*q + r)*256 + 32*w + 16*nt + m] = hiR[nt*4 + r];

    // acc chains: hi seeded with U_t, lo zero (summed before tanh)
    float4v a0h = { bf2f(un[0]), bf2f(un[1]), bf2f(un[2]), bf2f(un[3]) };
    float4v a1h = { bf2f(un[4]), bf2f(un[5]), bf2f(un[6]), bf2f(un[7]) };
    float4v a0l = { 0.f, 0.f, 0.f, 0.f };
    float4v a1l = { 0.f, 0.f, 0.f, 0.f };

    // prefetch U_{t+1} (row-major, coalesced; retires by next-step use)
    const int tn = (t < 99) ? t + 1 : 99;
    unsigned short unN[8];
    #pragma unroll
    for (int nt = 0; nt < 2; ++nt)
      #pragma unroll
      for (int r = 0; r < 4; ++r)
        unN[nt*4 + r] = U[((size_t)(c*100 + tn)*512 + b0 + 4*q + r)*256 + 32*w + 16*nt + m];

    const unsigned int* hrow = &hI[cur][m][0];
    #pragma unroll
    for (int kt = 0; kt < 8; ++kt){
      uint4 u0 = *(const uint4*)(hrow + 32*kt + 8*q);
      uint4 u1 = *(const uint4*)(hrow + 32*kt + 8*q + 4);
      union { short8 v; unsigned int d[4]; } ahi, alo;
      ahi.d[0] = __builtin_amdgcn_perm(u0.y, u0.x, 0x05040100u);
      ahi.d[1] = __builtin_amdgcn_perm(u0.w, u0.z, 0x05040100u);
      ahi.d[2] = __builtin_amdgcn_perm(u1.y, u1.x, 0x05040100u);
      ahi.d[3] = __builtin_amdgcn_perm(u1.w, u1.z, 0x05040100u);
      alo.d[0] = __builtin_amdgcn_perm(u0.y, u0.x, 0x07060302u);
      alo.d[1] = __builtin_amdgcn_perm(u0.w, u0.z, 0x07060302u);
      alo.d[2] = __builtin_amdgcn_perm(u1.y, u1.x, 0x07060302u);
      alo.d[3] = __builtin_amdgcn_perm(u1.w, u1.z, 0x07060302u);
      a0h = MFMA_BF16(ahi.v, qf[kt][0], a0h, 0,0,0);
      a1h = MFMA_BF16(ahi.v, qf[kt][1], a1h, 0,0,0);
      a0l = MFMA_BF16(alo.v, qf[kt][0], a0l, 0,0,0);
      a1l = MFMA_BF16(alo.v, qf[kt][1], a1l, 0,0,0);
    }

    float hn[8];
    hn[0] = ftanh(a0h.x + a0l.x); hn[1] = ftanh(a0h.y + a0l.y);
    hn[2] = ftanh(a0h.z + a0l.z); hn[3] = ftanh(a0h.w + a0l.w);
    hn[4] = ftanh(a1h.x + a1l.x); hn[5] = ftanh(a1h.y + a1l.y);
    hn[6] = ftanh(a1h.z + a1l.z); hn[7] = ftanh(a1h.w + a1l.w);

    // write h_{t+1} into NEXT buffer as packed hi|lo (8 x ds_write_b32)
    #pragma unroll
    for (int nt = 0; nt < 2; ++nt){
      const int col = 32*w + 16*nt + m;
      #pragma unroll
      for (int r = 0; r < 4; ++r){
        const int row = 4*q + r;
        float v = hn[nt*4 + r];
        unsigned short hi = f2bf(v);
        hiR[nt*4 + r] = hi;
        hI[nxt][row][col] = (unsigned int)hi | ((unsigned int)f2bf(v - bf2f(hi)) << 16);
      }
    }
    #pragma unroll
    for (int i = 0; i < 8; ++i) un[i] = unN[i];

    __syncthreads();   // single barrier per step
  }
}

// ---- kernC3: out = x@Nn + Hs@M2 + n0 via MFMA. 1200 blocks x 512 thr. (proven)
__global__ __launch_bounds__(512, 2)
void kernC3(const float* __restrict__ x, const unsigned short* __restrict__ Hs,
            const float* __restrict__ Nn, const float* __restrict__ M2,
            const float* __restrict__ n0, float* __restrict__ out){
  __shared__ unsigned short xs[128][136];
  const int m0 = blockIdx.x * 128;
  const int c  = m0 / 51200;
  const int w  = threadIdx.x >> 6;
  const int l  = threadIdx.x & 63;
  const int q  = l >> 4, m = l & 15;
  const int col = 16*w + m;
  const float* __restrict__ Nc  = Nn + (size_t)c * 16384;   // [128][128]
  const float* __restrict__ M2c = M2 + (size_t)c * 32768;   // [256][128]

  short8 bw[12];
  #pragma unroll
  for (int kt = 0; kt < 4; ++kt){
    union { short8 v; unsigned short u[8]; } tmp;
    #pragma unroll
    for (int j = 0; j < 8; ++j)
      tmp.u[j] = f2bf(Nc[(size_t)(32*kt + 8*q + j)*128 + col]);
    bw[kt] = tmp.v;
  }
  #pragma unroll
  for (int kt = 0; kt < 8; ++kt){
    union { short8 v; unsigned short u[8]; } tmp;
    #pragma unroll
    for (int j = 0; j < 8; ++j)
      tmp.u[j] = f2bf(M2c[(size_t)(32*kt + 8*q + j)*128 + col]);
    bw[4 + kt] = tmp.v;
  }
  const float nz = n0[c*128 + col];

  {
    const int r  = threadIdx.x >> 2;
    const int c0 = (threadIdx.x & 3) * 32;
    const float* xr = x + (size_t)(m0 + r)*128 + c0;
    #pragma unroll
    for (int i = 0; i < 8; ++i){
      float4 v = *(const float4*)(xr + 4*i);
      st_bf2(&xs[r][c0 + 4*i],     v.x, v.y);
      st_bf2(&xs[r][c0 + 4*i + 2], v.z, v.w);
    }
  }
  __syncthreads();

  #pragma unroll 1
  for (int mt = 0; mt < 8; ++mt){
    float4v aa = { nz, nz, nz, nz }, ab = { 0.f, 0.f, 0.f, 0.f };
    #pragma unroll
    for (int kt = 0; kt < 4; ++kt){
      short8 af = *(const short8*)&xs[16*mt + m][32*kt + 8*q];
      if (kt & 1) ab = MFMA_BF16(af, bw[kt], ab, 0,0,0);
      else        aa = MFMA_BF16(af, bw[kt], aa, 0,0,0);
    }
    const size_t mrow = (size_t)(m0 + 16*mt) + m;
    #pragma unroll
    for (int kt = 0; kt < 8; ++kt){
      short8 af = *(const short8*)&Hs[mrow*256 + 32*kt + 8*q];
      if (kt & 1) ab = MFMA_BF16(af, bw[4+kt], ab, 0,0,0);
      else        aa = MFMA_BF16(af, bw[4+kt], aa, 0,0,0);
    }
    float* ob = out + (size_t)(m0 + 16*mt + 4*q)*128 + col;
    ob[0]   = aa.x + ab.x;
    ob[128] = aa.y + ab.y;
    ob[256] = aa.z + ab.z;
    ob[384] = aa.w + ab.w;
  }
}

extern "C" void kernel_launch(void* const* d_in, const int* in_sizes, int n_in,
                              void* d_out, int out_size, void* d_ws, size_t ws_size,
                              hipStream_t stream){
  const float* x    = (const float*)d_in[0];
  const float* Wx   = (const float*)d_in[1];
  const float* bx   = (const float*)d_in[2];
  const float* encW = (const float*)d_in[3];
  const float* encb = (const float*)d_in[4];
  const float* Wqm  = (const float*)d_in[5];
  const float* bqm  = (const float*)d_in[6];
  const float* Wz   = (const float*)d_in[7];
  const float* bz   = (const float*)d_in[8];
  const float* decW = (const float*)d_in[9];
  const float* decb = (const float*)d_in[10];
  const float* Wpm  = (const float*)d_in[11];
  const float* bpm  = (const float*)d_in[12];
  const float* Wih  = (const float*)d_in[13];
  const float* Whh  = (const float*)d_in[14];
  const float* bih  = (const float*)d_in[15];
  const float* bhh  = (const float*)d_in[16];
  const float* h0   = (const float*)d_in[17];

  float* ws = (float*)d_ws;
  size_t off = 0;
  auto alloc = [&](size_t n){ float* p = ws + off; off += n; return p; };
  float* T1  = alloc(24576);  float* T2  = alloc(49152);  float* c0a = alloc(192);
  float* A   = alloc(49152);  float* Bm  = alloc(98304);  float* c0  = alloc(384);
  float* P   = alloc(98304);  float* Q   = alloc(196608); float* r   = alloc(768);
  float* D1  = alloc(49152);  float* E1  = alloc(98304);  float* m0a = alloc(384);
  float* R   = alloc(98304);  float* r0  = alloc(768);
  float* M1  = alloc(49152);  float* M2  = alloc(98304);  float* m0  = alloc(384);
  float* Nn  = alloc(49152);  float* n0  = alloc(384);
  // Hs: 39,321,600 bf16 elements = 19,660,800 float slots (full size).
  unsigned short* Hs = (unsigned short*)(ws + off); off += 19660800;
  // U (bf16, 78.64 MB, ROW-MAJOR) lives in d_out (exact fit); consumed by
  // kernB7 before kernC3 overwrites d_out with the final result.
  unsigned short* U  = (unsigned short*)d_out;

  hipLaunchKernelGGL(pre1, dim3(289),  dim3(256), 0, stream, encW, encb, Wqm, bqm, T1, T2, c0a);
  hipLaunchKernelGGL(pre2, dim3(578),  dim3(256), 0, stream, T1, T2, c0a, Wz, bz, A, Bm, c0);
  hipLaunchKernelGGL(pre3, dim3(1733), dim3(256), 0, stream, A, Bm, c0, Wih, Whh, bih, bhh,
                     decW, decb, P, Q, r, D1, E1, m0a);
  hipLaunchKernelGGL(pre4, dim3(965),  dim3(256), 0, stream, Wx, bx, P, r, D1, E1, m0a,
                     Wpm, bpm, R, r0, M1, M2, m0);
  hipLaunchKernelGGL(pre5, dim3(194),  dim3(256), 0, stream, Wx, bx, M1, m0, Nn, n0);
  hipLaunchKernelGGL(kernU2, dim3(1200), dim3(512), 0, stream, x, R, r0, U);
  hipLaunchKernelGGL(kernB7, dim3(96),   dim3(512), 0, stream, U, Q, h0, Hs);
  hipLaunchKernelGGL(kernC3, dim3(1200), dim3(512), 0, stream, x, Hs, Nn, M2, n0, (float*)d_out);
}

// Round 9
// 438.731 us; speedup vs baseline: 1.7366x; 1.1214x over previous
//
#include <hip/hip_runtime.h>
#include <hip/hip_bf16.h>
#include <cstdint>

// MCRNNVAE eval forward, algebraically collapsed:
//   h_{t+1} = tanh(x_t@R_c + r0_c + h_t@Q_c)
//   mu_t    = x_t@N_c + h_t@M2_c + n0_c
// R,Q,N,M2,r0,n0 precomputed from the raw weights (exact linear algebra).
// Round 13: kernB8 = proven kernB4 (137 us) MINUS the lo-correction plane:
// h feeds back as plain bf16. Halves the dominant LDS-read stream (16->8 b128
// per wave-step), MFMA count (32->16), and LDS writes (16->8). Error budget:
// Hs is already bf16-hi-only, so only the recurrence trajectory loses the
// lo@Q term (|lo|<=2^-9, |Q|~0.05 -> ~1e-3/step, contraction-damped); current
// absmax 0.0078 has 2.8x margin to the 0.0219 threshold. If this fails the
// absmax check, revert to kernB4 (hi/lo) — that line is then closed.

typedef __attribute__((ext_vector_type(8))) short short8;
typedef __attribute__((ext_vector_type(4))) float float4v;

__device__ __forceinline__ float bf2f(unsigned short u){
  union { unsigned int i; float f; } v; v.i = ((unsigned int)u) << 16; return v.f;
}
__device__ __forceinline__ unsigned short f2bf(float f){
  union { float f; unsigned int i; } v; v.f = f;
  unsigned int r = v.i + 0x7fffu + ((v.i >> 16) & 1u);
  return (unsigned short)(r >> 16);
}
__device__ __forceinline__ void st_bf2(unsigned short* p, float a, float b){
  unsigned int pa = f2bf(a), pb = f2bf(b);
  *(unsigned int*)p = pa | (pb << 16);
}
__device__ __forceinline__ float ftanh(float x){
  x = fminf(15.f, fmaxf(-15.f, x));
  float e = __expf(2.f * x);
  return (e - 1.f) * __builtin_amdgcn_rcpf(e + 1.f);
}

__device__ __forceinline__ float dotSB(const float* __restrict__ a,
                                       const float* __restrict__ b, int K, int ldb){
  float s = 0.f;
  #pragma unroll 4
  for (int k = 0; k < K; ++k) s = fmaf(a[k], b[(size_t)k * ldb], s);
  return s;
}

// ---- precompute stage 1: T1 = We1@Wqm, T2 = We2@Wqm, c0a = be@Wqm + bqm
__global__ void pre1(const float* __restrict__ encW, const float* __restrict__ encb,
                     const float* __restrict__ Wqm, const float* __restrict__ bqm,
                     float* __restrict__ T1, float* __restrict__ T2, float* __restrict__ c0a){
  int i = blockIdx.x * 256 + threadIdx.x;
  if (i < 24576){
    int c = i >> 13, rr = (i >> 6) & 127, l = i & 63;
    T1[i] = dotSB(encW + ((size_t)c*384 + rr)*128, Wqm + (size_t)c*8192 + l, 128, 64);
  } else if (i < 73728){
    int j = i - 24576; int c = j >> 14, rr = (j >> 6) & 255, l = j & 63;
    T2[j] = dotSB(encW + ((size_t)c*384 + 128 + rr)*128, Wqm + (size_t)c*8192 + l, 128, 64);
  } else if (i < 73920){
    int j = i - 73728; int c = j >> 6, l = j & 63;
    c0a[j] = dotSB(encb + c*128, Wqm + (size_t)c*8192 + l, 128, 64) + bqm[j];
  }
}

// ---- stage 2: A = T1@Wz, Bm = T2@Wz, c0 = c0a@Wz + bz
__global__ void pre2(const float* __restrict__ T1, const float* __restrict__ T2,
                     const float* __restrict__ c0a, const float* __restrict__ Wz,
                     const float* __restrict__ bz,
                     float* __restrict__ A, float* __restrict__ Bm, float* __restrict__ c0){
  int i = blockIdx.x * 256 + threadIdx.x;
  if (i < 49152){
    int c = i >> 14, rr = (i >> 7) & 127, n = i & 127;
    A[i] = dotSB(T1 + ((size_t)c*128 + rr)*64, Wz + n, 64, 128);
  } else if (i < 147456){
    int j = i - 49152; int c = j >> 15, rr = (j >> 7) & 255, n = j & 127;
    Bm[j] = dotSB(T2 + ((size_t)c*256 + rr)*64, Wz + n, 64, 128);
  } else if (i < 147840){
    int j = i - 147456; int c = j >> 7, n = j & 127;
    c0[j] = dotSB(c0a + c*64, Wz + n, 64, 128) + bz[n];
  }
}

// ---- stage 3: P = Wi1 + A@Wi2; Q = Whh + Bm@Wi2; r = c0@Wi2 + bih + bhh;
//               D1 = A@Wd1; E1 = Wd2 + Bm@Wd1; m0a = c0@Wd1 + bd
__global__ void pre3(const float* __restrict__ A, const float* __restrict__ Bm,
                     const float* __restrict__ c0, const float* __restrict__ Wih,
                     const float* __restrict__ Whh, const float* __restrict__ bih,
                     const float* __restrict__ bhh, const float* __restrict__ decW,
                     const float* __restrict__ decb,
                     float* __restrict__ P, float* __restrict__ Q, float* __restrict__ r,
                     float* __restrict__ D1, float* __restrict__ E1, float* __restrict__ m0a){
  int i = blockIdx.x * 256 + threadIdx.x;
  const float* Wi2 = Wih + 128*256;
  if (i < 98304){
    int c = i >> 15, rr = (i >> 8) & 127, n = i & 255;
    P[i] = Wih[rr*256 + n] + dotSB(A + ((size_t)c*128 + rr)*128, Wi2 + n, 128, 256);
  } else if (i < 294912){
    int j = i - 98304; int c = j >> 16, rr = (j >> 8) & 255, n = j & 255;
    Q[j] = Whh[rr*256 + n] + dotSB(Bm + ((size_t)c*256 + rr)*128, Wi2 + n, 128, 256);
  } else if (i < 295680){
    int j = i - 294912; int c = j >> 8, n = j & 255;
    r[j] = dotSB(c0 + c*128, Wi2 + n, 128, 256) + bih[n] + bhh[n];
  } else if (i < 344832){
    int j = i - 295680; int c = j >> 14, rr = (j >> 7) & 127, n = j & 127;
    D1[j] = dotSB(A + ((size_t)c*128 + rr)*128, decW + (size_t)c*49152 + n, 128, 128);
  } else if (i < 443136){
    int j = i - 344832; int c = j >> 15, rr = (j >> 7) & 255, n = j & 127;
    E1[j] = decW[(size_t)c*49152 + (size_t)(128 + rr)*128 + n]
          + dotSB(Bm + ((size_t)c*256 + rr)*128, decW + (size_t)c*49152 + n, 128, 128);
  } else if (i < 443520){
    int j = i - 443136; int c = j >> 7, n = j & 127;
    m0a[j] = dotSB(c0 + c*128, decW + (size_t)c*49152 + n, 128, 128) + decb[j];
  }
}

// ---- stage 4: R = Wx@P; r0 = bx@P + r; M1 = D1@Wpm; M2 = E1@Wpm; m0 = m0a@Wpm + bpm
__global__ void pre4(const float* __restrict__ Wx, const float* __restrict__ bx,
                     const float* __restrict__ P, const float* __restrict__ r,
                     const float* __restrict__ D1, const float* __restrict__ E1,
                     const float* __restrict__ m0a, const float* __restrict__ Wpm,
                     const float* __restrict__ bpm,
                     float* __restrict__ R, float* __restrict__ r0,
                     float* __restrict__ M1, float* __restrict__ M2, float* __restrict__ m0){
  int i = blockIdx.x * 256 + threadIdx.x;
  if (i < 98304){
    int c = i >> 15, rr = (i >> 8) & 127, n = i & 255;
    R[i] = dotSB(Wx + ((size_t)c*128 + rr)*128, P + (size_t)c*32768 + n, 128, 256);
  } else if (i < 99072){
    int j = i - 98304; int c = j >> 8, n = j & 255;
    r0[j] = dotSB(bx + c*128, P + (size_t)c*32768 + n, 128, 256) + r[j];
  } else if (i < 148224){
    int j = i - 99072; int c = j >> 14, rr = (j >> 7) & 127, n = j & 127;
    M1[j] = dotSB(D1 + ((size_t)c*128 + rr)*128, Wpm + (size_t)c*16384 + n, 128, 128);
  } else if (i < 246528){
    int j = i - 148224; int c = j >> 15, rr = (j >> 7) & 255, n = j & 127;
    M2[j] = dotSB(E1 + ((size_t)c*256 + rr)*128, Wpm + (size_t)c*16384 + n, 128, 128);
  } else if (i < 246912){
    int j = i - 246528; int c = j >> 7, n = j & 127;
    m0[j] = dotSB(m0a + c*128, Wpm + (size_t)c*16384 + n, 128, 128) + bpm[j];
  }
}

// ---- stage 5: Nn = Wx@M1; n0 = bx@M1 + m0
__global__ void pre5(const float* __restrict__ Wx, const float* __restrict__ bx,
                     const float* __restrict__ M1, const float* __restrict__ m0,
                     float* __restrict__ Nn, float* __restrict__ n0){
  int i = blockIdx.x * 256 + threadIdx.x;
  if (i < 49152){
    int c = i >> 14, rr = (i >> 7) & 127, n = i & 127;
    Nn[i] = dotSB(Wx + ((size_t)c*128 + rr)*128, M1 + (size_t)c*16384 + n, 128, 128);
  } else if (i < 49536){
    int j = i - 49152; int c = j >> 7, n = j & 127;
    n0[j] = dotSB(bx + c*128, M1 + (size_t)c*16384 + n, 128, 128) + m0[j];
  }
}

#define MFMA_BF16 __builtin_amdgcn_mfma_f32_16x16x32_bf16

// ---- kernU2: U = x@R + r0 (bf16, ROW-MAJOR) via MFMA. 1200 blocks x 512 thr.
// (proven round-0/3 version — coalesced stores, lanes m consecutive)
__global__ __launch_bounds__(512, 2)
void kernU2(const float* __restrict__ x, const float* __restrict__ Rg,
            const float* __restrict__ r0g, unsigned short* __restrict__ U){
  __shared__ unsigned short xs[128][136];
  const int m0 = blockIdx.x * 128;
  const int c  = m0 / 51200;                   // 400 blocks/channel, no straddle
  const int w  = threadIdx.x >> 6;
  const int l  = threadIdx.x & 63;
  const int q  = l >> 4, m = l & 15;
  const float* __restrict__ Rc = Rg + (size_t)c * 32768;   // [128][256]

  short8 rf[4][2];
  #pragma unroll
  for (int kt = 0; kt < 4; ++kt)
    #pragma unroll
    for (int nt = 0; nt < 2; ++nt){
      union { short8 v; unsigned short u[8]; } tmp;
      const int col = 32*w + 16*nt + m;
      #pragma unroll
      for (int j = 0; j < 8; ++j)
        tmp.u[j] = f2bf(Rc[(size_t)(32*kt + 8*q + j)*256 + col]);
      rf[kt][nt] = tmp.v;
    }
  const float r0v0 = r0g[c*256 + 32*w + m];
  const float r0v1 = r0g[c*256 + 32*w + 16 + m];

  {
    const int r  = threadIdx.x >> 2;
    const int c0 = (threadIdx.x & 3) * 32;
    const float* xr = x + (size_t)(m0 + r)*128 + c0;
    #pragma unroll
    for (int i = 0; i < 8; ++i){
      float4 v = *(const float4*)(xr + 4*i);
      st_bf2(&xs[r][c0 + 4*i],     v.x, v.y);
      st_bf2(&xs[r][c0 + 4*i + 2], v.z, v.w);
    }
  }
  __syncthreads();

  #pragma unroll 1
  for (int mt = 0; mt < 8; ++mt){
    float4v a0 = { r0v0, r0v0, r0v0, r0v0 };
    float4v a1 = { r0v1, r0v1, r0v1, r0v1 };
    #pragma unroll
    for (int kt = 0; kt < 4; ++kt){
      short8 af = *(const short8*)&xs[16*mt + m][32*kt + 8*q];
      a0 = MFMA_BF16(af, rf[kt][0], a0, 0,0,0);
      a1 = MFMA_BF16(af, rf[kt][1], a1, 0,0,0);
    }
    unsigned short* ub = U + (size_t)(m0 + 16*mt + 4*q)*256;
    ub[0*256 + 32*w + m]      = f2bf(a0.x);
    ub[1*256 + 32*w + m]      = f2bf(a0.y);
    ub[2*256 + 32*w + m]      = f2bf(a0.z);
    ub[3*256 + 32*w + m]      = f2bf(a0.w);
    ub[0*256 + 32*w + 16 + m] = f2bf(a1.x);
    ub[1*256 + 32*w + 16 + m] = f2bf(a1.y);
    ub[2*256 + 32*w + 16 + m] = f2bf(a1.z);
    ub[3*256 + 32*w + 16 + m] = f2bf(a1.w);
  }
}

// ---- kernB8: recurrence h_{t+1} = tanh(U_t + h_t@Q_c) via MFMA, bf16 h.
// 96 blocks x 512 thr (8 waves). = kernB4 minus the lo-correction plane:
// 8 ds_read_b128 + 16 MFMA + 8 ds_write_b16 per wave-step (all halved).
// Double-buffered hH -> single __syncthreads per step; 2 acc chains.
__global__ __launch_bounds__(512, 2)
void kernB8(const unsigned short* __restrict__ U, const float* __restrict__ Qg,
            const float* __restrict__ h0, unsigned short* __restrict__ Hs){
  __shared__ unsigned short hH[2][16][264];
  const int c  = blockIdx.x >> 5;
  const int b0 = (blockIdx.x & 31) << 4;
  const int w  = threadIdx.x >> 6;
  const int l  = threadIdx.x & 63;
  const int q  = l >> 4, m = l & 15;
  const float* __restrict__ Qc = Qg + (size_t)c * 65536;

  short8 qf[8][2];
  #pragma unroll
  for (int kt = 0; kt < 8; ++kt)
    #pragma unroll
    for (int nt = 0; nt < 2; ++nt){
      union { short8 v; unsigned short u[8]; } tmp;
      const int col = 32*w + 16*nt + m;
      #pragma unroll
      for (int j = 0; j < 8; ++j)
        tmp.u[j] = f2bf(Qc[(size_t)(32*kt + 8*q + j)*256 + col]);
      qf[kt][nt] = tmp.v;
    }

  unsigned short hiR[8];
  #pragma unroll
  for (int nt = 0; nt < 2; ++nt){
    const int col = 32*w + 16*nt + m;
    #pragma unroll
    for (int r = 0; r < 4; ++r){
      const int row = 4*q + r;
      unsigned short hi = f2bf(h0[((size_t)c*512 + b0 + row)*256 + col]);
      hiR[nt*4 + r] = hi;
      hH[0][row][col] = hi;
    }
  }
  __syncthreads();

  unsigned short un[8];
  #pragma unroll
  for (int nt = 0; nt < 2; ++nt)
    #pragma unroll
    for (int r = 0; r < 4; ++r)
      un[nt*4 + r] = U[((size_t)(c*100 + 0)*512 + b0 + 4*q + r)*256 + 32*w + 16*nt + m];

  #pragma unroll 1
  for (int t = 0; t < 100; ++t){
    const int cur = t & 1, nxt = cur ^ 1;

    // store h_t (bf16) to Hs — fire-and-forget
    const size_t rowbase = (size_t)(c*100 + t)*512 + b0;
    #pragma unroll
    for (int nt = 0; nt < 2; ++nt)
      #pragma unroll
      for (int r = 0; r < 4; ++r)
        Hs[(rowbase + 4*q + r)*256 + 32*w + 16*nt + m] = hiR[nt*4 + r];

    // two independent acc chains (len 8 each), seeded with U_t
    float4v a0 = { bf2f(un[0]), bf2f(un[1]), bf2f(un[2]), bf2f(un[3]) };
    float4v a1 = { bf2f(un[4]), bf2f(un[5]), bf2f(un[6]), bf2f(un[7]) };

    // prefetch U_{t+1} (row-major, coalesced; retires by next-step use)
    const int tn = (t < 99) ? t + 1 : 99;
    unsigned short unN[8];
    #pragma unroll
    for (int nt = 0; nt < 2; ++nt)
      #pragma unroll
      for (int r = 0; r < 4; ++r)
        unN[nt*4 + r] = U[((size_t)(c*100 + tn)*512 + b0 + 4*q + r)*256 + 32*w + 16*nt + m];

    #pragma unroll
    for (int kt = 0; kt < 8; ++kt){
      short8 ah = *(const short8*)&hH[cur][m][32*kt + 8*q];
      a0 = MFMA_BF16(ah, qf[kt][0], a0, 0,0,0);
      a1 = MFMA_BF16(ah, qf[kt][1], a1, 0,0,0);
    }

    float hn[8];
    hn[0] = ftanh(a0.x); hn[1] = ftanh(a0.y); hn[2] = ftanh(a0.z); hn[3] = ftanh(a0.w);
    hn[4] = ftanh(a1.x); hn[5] = ftanh(a1.y); hn[6] = ftanh(a1.z); hn[7] = ftanh(a1.w);

    // write h_{t+1} (bf16) into NEXT buffer
    #pragma unroll
    for (int nt = 0; nt < 2; ++nt){
      const int col = 32*w + 16*nt + m;
      #pragma unroll
      for (int r = 0; r < 4; ++r){
        const int row = 4*q + r;
        unsigned short hi = f2bf(hn[nt*4 + r]);
        hiR[nt*4 + r] = hi;
        hH[nxt][row][col] = hi;
      }
    }
    #pragma unroll
    for (int i = 0; i < 8; ++i) un[i] = unN[i];

    __syncthreads();   // single barrier per step
  }
}

// ---- kernC3: out = x@Nn + Hs@M2 + n0 via MFMA. 1200 blocks x 512 thr. (proven)
__global__ __launch_bounds__(512, 2)
void kernC3(const float* __restrict__ x, const unsigned short* __restrict__ Hs,
            const float* __restrict__ Nn, const float* __restrict__ M2,
            const float* __restrict__ n0, float* __restrict__ out){
  __shared__ unsigned short xs[128][136];
  const int m0 = blockIdx.x * 128;
  const int c  = m0 / 51200;
  const int w  = threadIdx.x >> 6;
  const int l  = threadIdx.x & 63;
  const int q  = l >> 4, m = l & 15;
  const int col = 16*w + m;
  const float* __restrict__ Nc  = Nn + (size_t)c * 16384;   // [128][128]
  const float* __restrict__ M2c = M2 + (size_t)c * 32768;   // [256][128]

  short8 bw[12];
  #pragma unroll
  for (int kt = 0; kt < 4; ++kt){
    union { short8 v; unsigned short u[8]; } tmp;
    #pragma unroll
    for (int j = 0; j < 8; ++j)
      tmp.u[j] = f2bf(Nc[(size_t)(32*kt + 8*q + j)*128 + col]);
    bw[kt] = tmp.v;
  }
  #pragma unroll
  for (int kt = 0; kt < 8; ++kt){
    union { short8 v; unsigned short u[8]; } tmp;
    #pragma unroll
    for (int j = 0; j < 8; ++j)
      tmp.u[j] = f2bf(M2c[(size_t)(32*kt + 8*q + j)*128 + col]);
    bw[4 + kt] = tmp.v;
  }
  const float nz = n0[c*128 + col];

  {
    const int r  = threadIdx.x >> 2;
    const int c0 = (threadIdx.x & 3) * 32;
    const float* xr = x + (size_t)(m0 + r)*128 + c0;
    #pragma unroll
    for (int i = 0; i < 8; ++i){
      float4 v = *(const float4*)(xr + 4*i);
      st_bf2(&xs[r][c0 + 4*i],     v.x, v.y);
      st_bf2(&xs[r][c0 + 4*i + 2], v.z, v.w);
    }
  }
  __syncthreads();

  #pragma unroll 1
  for (int mt = 0; mt < 8; ++mt){
    float4v aa = { nz, nz, nz, nz }, ab = { 0.f, 0.f, 0.f, 0.f };
    #pragma unroll
    for (int kt = 0; kt < 4; ++kt){
      short8 af = *(const short8*)&xs[16*mt + m][32*kt + 8*q];
      if (kt & 1) ab = MFMA_BF16(af, bw[kt], ab, 0,0,0);
      else        aa = MFMA_BF16(af, bw[kt], aa, 0,0,0);
    }
    const size_t mrow = (size_t)(m0 + 16*mt) + m;
    #pragma unroll
    for (int kt = 0; kt < 8; ++kt){
      short8 af = *(const short8*)&Hs[mrow*256 + 32*kt + 8*q];
      if (kt & 1) ab = MFMA_BF16(af, bw[4+kt], ab, 0,0,0);
      else        aa = MFMA_BF16(af, bw[4+kt], aa, 0,0,0);
    }
    float* ob = out + (size_t)(m0 + 16*mt + 4*q)*128 + col;
    ob[0]   = aa.x + ab.x;
    ob[128] = aa.y + ab.y;
    ob[256] = aa.z + ab.z;
    ob[384] = aa.w + ab.w;
  }
}

extern "C" void kernel_launch(void* const* d_in, const int* in_sizes, int n_in,
                              void* d_out, int out_size, void* d_ws, size_t ws_size,
                              hipStream_t stream){
  const float* x    = (const float*)d_in[0];
  const float* Wx   = (const float*)d_in[1];
  const float* bx   = (const float*)d_in[2];
  const float* encW = (const float*)d_in[3];
  const float* encb = (const float*)d_in[4];
  const float* Wqm  = (const float*)d_in[5];
  const float* bqm  = (const float*)d_in[6];
  const float* Wz   = (const float*)d_in[7];
  const float* bz   = (const float*)d_in[8];
  const float* decW = (const float*)d_in[9];
  const float* decb = (const float*)d_in[10];
  const float* Wpm  = (const float*)d_in[11];
  const float* bpm  = (const float*)d_in[12];
  const float* Wih  = (const float*)d_in[13];
  const float* Whh  = (const float*)d_in[14];
  const float* bih  = (const float*)d_in[15];
  const float* bhh  = (const float*)d_in[16];
  const float* h0   = (const float*)d_in[17];

  float* ws = (float*)d_ws;
  size_t off = 0;
  auto alloc = [&](size_t n){ float* p = ws + off; off += n; return p; };
  float* T1  = alloc(24576);  float* T2  = alloc(49152);  float* c0a = alloc(192);
  float* A   = alloc(49152);  float* Bm  = alloc(98304);  float* c0  = alloc(384);
  float* P   = alloc(98304);  float* Q   = alloc(196608); float* r   = alloc(768);
  float* D1  = alloc(49152);  float* E1  = alloc(98304);  float* m0a = alloc(384);
  float* R   = alloc(98304);  float* r0  = alloc(768);
  float* M1  = alloc(49152);  float* M2  = alloc(98304);  float* m0  = alloc(384);
  float* Nn  = alloc(49152);  float* n0  = alloc(384);
  // Hs: 39,321,600 bf16 elements = 19,660,800 float slots (full size).
  unsigned short* Hs = (unsigned short*)(ws + off); off += 19660800;
  // U (bf16, 78.64 MB, ROW-MAJOR) lives in d_out (exact fit); consumed by
  // kernB8 before kernC3 overwrites d_out with the final result.
  unsigned short* U  = (unsigned short*)d_out;

  hipLaunchKernelGGL(pre1, dim3(289),  dim3(256), 0, stream, encW, encb, Wqm, bqm, T1, T2, c0a);
  hipLaunchKernelGGL(pre2, dim3(578),  dim3(256), 0, stream, T1, T2, c0a, Wz, bz, A, Bm, c0);
  hipLaunchKernelGGL(pre3, dim3(1733), dim3(256), 0, stream, A, Bm, c0, Wih, Whh, bih, bhh,
                     decW, decb, P, Q, r, D1, E1, m0a);
  hipLaunchKernelGGL(pre4, dim3(965),  dim3(256), 0, stream, Wx, bx, P, r, D1, E1, m0a,
                     Wpm, bpm, R, r0, M1, M2, m0);
  hipLaunchKernelGGL(pre5, dim3(194),  dim3(256), 0, stream, Wx, bx, M1, m0, Nn, n0);
  hipLaunchKernelGGL(kernU2, dim3(1200), dim3(512), 0, stream, x, R, r0, U);
  hipLaunchKernelGGL(kernB8, dim3(96),   dim3(512), 0, stream, U, Q, h0, Hs);
  hipLaunchKernelGGL(kernC3, dim3(1200), dim3(512), 0, stream, x, Hs, Nn, M2, n0, (float*)d_out);
}